// Round 1
// baseline (1391.401 us; speedup 1.0000x reference)
//
#include <hip/hip_runtime.h>

#define NN 20000
#define NE 320000
#define NB 64

// ---------------- CSR build ----------------

__global__ __launch_bounds__(256) void k_count_edges(const int* __restrict__ ei, const int* __restrict__ et,
                                                     int* __restrict__ deg, int* __restrict__ cntrel) {
    int e = blockIdx.x * 256 + threadIdx.x;
    if (e >= NE) return;
    int dst = ei[NE + e];
    atomicAdd(&deg[dst], 1);
    atomicAdd(&cntrel[et[e] * NN + dst], 1);
}

__global__ __launch_bounds__(256) void k_scan_local(const int* __restrict__ deg, int* __restrict__ off,
                                                    int* __restrict__ csum, int n) {
    __shared__ int sh[256];
    int base = blockIdx.x * 256, tid = threadIdx.x;
    int v = (base + tid < n) ? deg[base + tid] : 0;
    sh[tid] = v; __syncthreads();
    for (int o = 1; o < 256; o <<= 1) {
        int t = (tid >= o) ? sh[tid - o] : 0;
        __syncthreads();
        sh[tid] += t;
        __syncthreads();
    }
    if (base + tid < n) off[base + tid] = sh[tid] - v;  // exclusive
    if (tid == 255) csum[blockIdx.x] = sh[255];
}

__global__ void k_scan_csum(int* __restrict__ csum, int* __restrict__ offN, int nc) {
    __shared__ int sh[128];
    int tid = threadIdx.x;
    int v = (tid < nc) ? csum[tid] : 0;
    sh[tid] = v; __syncthreads();
    for (int o = 1; o < 128; o <<= 1) {
        int t = (tid >= o) ? sh[tid - o] : 0;
        __syncthreads();
        sh[tid] += t;
        __syncthreads();
    }
    if (tid < nc) csum[tid] = sh[tid] - v;  // exclusive
    if (tid == 127) offN[0] = sh[127];      // total (== NE) -> off[n]
}

__global__ __launch_bounds__(256) void k_scan_add(int* __restrict__ off, const int* __restrict__ csum, int n) {
    int i = blockIdx.x * 256 + threadIdx.x;
    if (i < n) off[i] += csum[blockIdx.x];
}

__global__ __launch_bounds__(256) void k_fill(const int* __restrict__ ei, const int* __restrict__ et,
                                              const int* __restrict__ off, int* __restrict__ cursor,
                                              int* __restrict__ adj) {
    int e = blockIdx.x * 256 + threadIdx.x;
    if (e >= NE) return;
    int src = ei[e], dst = ei[NE + e], r = et[e];
    int pos = atomicAdd(&cursor[dst], 1);
    adj[off[dst] + pos] = src | (r << 28);
}

__global__ void k_invcnt(const int* __restrict__ cntrel, float* __restrict__ inv) {
    int i = blockIdx.x * 256 + threadIdx.x;
    if (i >= 2 * NN) return;
    int c = cntrel[i];
    inv[i] = 1.0f / (float)(c > 0 ? c : 1);
}

// ---------------- GEMM: out_root = A@w_root + b ; h0 = A@w_rel[0] ; h1 = A@w_rel[1] ----------------
// A [M,K] row-major, weights [K,C] row-major. blockIdx.z selects which product.

__global__ __launch_bounds__(256) void k_gemm3(const float* __restrict__ A, int K,
                                               const float* __restrict__ wroot, const float* __restrict__ wrel,
                                               const float* __restrict__ bias,
                                               float* __restrict__ outRoot, float* __restrict__ h0,
                                               float* __restrict__ h1, int C, int M) {
    __shared__ float As[16][64];  // transposed: As[k][row]
    __shared__ float Bs[16][64];  // Bs[k][col]
    int z = blockIdx.z;
    const float* Bmat = (z == 0) ? wroot : wrel + (size_t)(z - 1) * K * C;
    float* D = (z == 0) ? outRoot : (z == 1 ? h0 : h1);
    int tid = threadIdx.x;
    int tx = tid & 15, ty = tid >> 4;
    int rowTile = blockIdx.y * 64, colTile = blockIdx.x * 64;
    float acc[4][4] = {};
    int rA = tid >> 2, kA = (tid & 3) * 4;
    int kB = tid >> 4, cB = (tid & 15) * 4;

    for (int k0 = 0; k0 < K; k0 += 16) {
        int grow = rowTile + rA;
        float4 av;
        if (grow < M) av = *(const float4*)&A[(size_t)grow * K + k0 + kA];
        else av = make_float4(0.f, 0.f, 0.f, 0.f);
        As[kA + 0][rA] = av.x; As[kA + 1][rA] = av.y; As[kA + 2][rA] = av.z; As[kA + 3][rA] = av.w;
        *(float4*)&Bs[kB][cB] = *(const float4*)&Bmat[(size_t)(k0 + kB) * C + colTile + cB];
        __syncthreads();
#pragma unroll
        for (int kk = 0; kk < 16; kk++) {
            float4 a = *(const float4*)&As[kk][ty * 4];
            float4 b = *(const float4*)&Bs[kk][tx * 4];
            acc[0][0] += a.x * b.x; acc[0][1] += a.x * b.y; acc[0][2] += a.x * b.z; acc[0][3] += a.x * b.w;
            acc[1][0] += a.y * b.x; acc[1][1] += a.y * b.y; acc[1][2] += a.y * b.z; acc[1][3] += a.y * b.w;
            acc[2][0] += a.z * b.x; acc[2][1] += a.z * b.y; acc[2][2] += a.z * b.z; acc[2][3] += a.z * b.w;
            acc[3][0] += a.w * b.x; acc[3][1] += a.w * b.y; acc[3][2] += a.w * b.z; acc[3][3] += a.w * b.w;
        }
        __syncthreads();
    }
    float bj[4] = {0.f, 0.f, 0.f, 0.f};
    if (z == 0) {
        bj[0] = bias[colTile + tx * 4 + 0];
        bj[1] = bias[colTile + tx * 4 + 1];
        bj[2] = bias[colTile + tx * 4 + 2];
        bj[3] = bias[colTile + tx * 4 + 3];
    }
#pragma unroll
    for (int i = 0; i < 4; i++) {
        int grow = rowTile + ty * 4 + i;
        if (grow < M) {
            float4 o = make_float4(acc[i][0] + bj[0], acc[i][1] + bj[1], acc[i][2] + bj[2], acc[i][3] + bj[3]);
            *(float4*)&D[(size_t)grow * C + colTile + tx * 4] = o;
        }
    }
}

// ---------------- per-node mean aggregation (CSR), out += sum_r s_r/cnt_r ----------------

template <int C>
__global__ __launch_bounds__(256) void k_aggregate(const int* __restrict__ off, const int* __restrict__ adj,
                                                   const float* __restrict__ inv, const float* __restrict__ h0,
                                                   const float* __restrict__ h1, float* __restrict__ out) {
    int wv = threadIdx.x >> 6, lane = threadIdx.x & 63;
    int node = blockIdx.x * 4 + wv;
    if (node >= NN) return;
    int s = off[node], e = off[node + 1];
    float w0 = inv[node], w1 = inv[NN + node];
    if (C == 256) {
        float4 acc = make_float4(0.f, 0.f, 0.f, 0.f);
        for (int i = s; i < e; i++) {
            int v = adj[i];
            int src = v & 0x0FFFFFFF, rel = v >> 28;
            const float* h = rel ? h1 : h0;
            float w = rel ? w1 : w0;
            float4 x = *(const float4*)&h[(size_t)src * 256 + lane * 4];
            acc.x += w * x.x; acc.y += w * x.y; acc.z += w * x.z; acc.w += w * x.w;
        }
        float* p = &out[(size_t)node * 256 + lane * 4];
        float4 o = *(float4*)p;
        o.x += acc.x; o.y += acc.y; o.z += acc.z; o.w += acc.w;
        *(float4*)p = o;
    } else {
        float2 acc = make_float2(0.f, 0.f);
        for (int i = s; i < e; i++) {
            int v = adj[i];
            int src = v & 0x0FFFFFFF, rel = v >> 28;
            const float* h = rel ? h1 : h0;
            float w = rel ? w1 : w0;
            float2 x = *(const float2*)&h[(size_t)src * 128 + lane * 2];
            acc.x += w * x.x; acc.y += w * x.y;
        }
        float* p = &out[(size_t)node * 128 + lane * 2];
        float2 o = *(float2*)p;
        o.x += acc.x; o.y += acc.y;
        *(float2*)p = o;
    }
}

// ---------------- batchnorm + leaky ----------------

__global__ __launch_bounds__(256) void k_bnstats(const float* __restrict__ x, float* __restrict__ sums, int C, int M) {
    int tid = threadIdx.x;
    int groups = 256 / C;             // 1 (C=256) or 2 (C=128)
    int col = tid & (C - 1);
    int rg = tid / C;
    float s = 0.f, s2 = 0.f;
    for (int row = blockIdx.x * groups + rg; row < M; row += gridDim.x * groups) {
        float v = x[(size_t)row * C + col];
        s += v; s2 += v * v;
    }
    atomicAdd(&sums[col], s);
    atomicAdd(&sums[C + col], s2);
}

__global__ void k_bnfinal(const float* __restrict__ sums, const float* __restrict__ g, const float* __restrict__ be,
                          float* __restrict__ ss, int C, float invM) {
    int c = threadIdx.x;
    if (c < C) {
        float mu = sums[c] * invM;
        float var = sums[C + c] * invM - mu * mu;
        float sc = g[c] * rsqrtf(var + 1e-5f);
        ss[c] = sc;
        ss[C + c] = be[c] - mu * sc;
    }
}

__global__ __launch_bounds__(256) void k_bnapply(float* __restrict__ x, const float* __restrict__ ss, int C, int M) {
    int i = blockIdx.x * 256 + threadIdx.x;
    int total4 = M * C / 4;
    if (i >= total4) return;
    float4 v = *(float4*)&x[(size_t)i * 4];
    int c0 = (i * 4) & (C - 1);
    float y0 = v.x * ss[c0 + 0] + ss[C + c0 + 0];
    float y1 = v.y * ss[c0 + 1] + ss[C + c0 + 1];
    float y2 = v.z * ss[c0 + 2] + ss[C + c0 + 2];
    float y3 = v.w * ss[c0 + 3] + ss[C + c0 + 3];
    v.x = y0 >= 0.f ? y0 : 0.01f * y0;
    v.y = y1 >= 0.f ? y1 : 0.01f * y1;
    v.z = y2 >= 0.f ? y2 : 0.01f * y2;
    v.w = y3 >= 0.f ? y3 : 0.01f * y3;
    *(float4*)&x[(size_t)i * 4] = v;
}

// ---------------- pooling ----------------

__global__ void k_gcnt(const int* __restrict__ batch, int* __restrict__ gcnt) {
    int n = blockIdx.x * 256 + threadIdx.x;
    if (n < NN) atomicAdd(&gcnt[batch[n]], 1);
}

__global__ void k_goff(const int* __restrict__ gcnt, int* __restrict__ goff) {
    if (threadIdx.x == 0) {
        int run = 0;
        for (int i = 0; i < NB; i++) { goff[i] = run; run += gcnt[i]; }
        goff[NB] = run;
    }
}

__global__ void k_pool(const float* __restrict__ x, const int* __restrict__ goff, float* __restrict__ out) {
    int b = blockIdx.x;
    int t = threadIdx.x;  // 128 threads = O columns
    int s = goff[b], e = goff[b + 1];
    float acc = 0.f;
    for (int r = s; r < e; r++) acc += x[(size_t)r * 128 + t];
    int cnt = e - s;
    out[b * 128 + t] = acc / (float)(cnt > 0 ? cnt : 1);
}

// ---------------- host orchestration ----------------

extern "C" void kernel_launch(void* const* d_in, const int* in_sizes, int n_in,
                              void* d_out, int out_size, void* d_ws, size_t ws_size,
                              hipStream_t stream) {
    const float* x_t = (const float*)d_in[0];
    const float* x_p = (const float*)d_in[1];
    const int* ei_t = (const int*)d_in[2];
    const int* et_t = (const int*)d_in[3];
    const int* bat_t = (const int*)d_in[4];
    const int* ei_p = (const int*)d_in[5];
    const int* et_p = (const int*)d_in[6];
    const int* bat_p = (const int*)d_in[7];
    const float* w_t1_rel = (const float*)d_in[8];
    const float* w_t1_root = (const float*)d_in[9];
    const float* b_t1 = (const float*)d_in[10];
    const float* w_t2_rel = (const float*)d_in[11];
    const float* w_t2_root = (const float*)d_in[12];
    const float* b_t2 = (const float*)d_in[13];
    const float* w_p1_rel = (const float*)d_in[14];
    const float* w_p1_root = (const float*)d_in[15];
    const float* b_p1 = (const float*)d_in[16];
    const float* w_p2_rel = (const float*)d_in[17];
    const float* w_p2_root = (const float*)d_in[18];
    const float* b_p2 = (const float*)d_in[19];
    const float* g_t1 = (const float*)d_in[20]; const float* be_t1 = (const float*)d_in[21];
    const float* g_t2 = (const float*)d_in[22]; const float* be_t2 = (const float*)d_in[23];
    const float* g_p1 = (const float*)d_in[24]; const float* be_p1 = (const float*)d_in[25];
    const float* g_p2 = (const float*)d_in[26]; const float* be_p2 = (const float*)d_in[27];

    char* wp = (char*)d_ws;
    auto alloc = [&](size_t b) -> void* {
        void* p = (void*)wp;
        wp += (b + 255) & ~(size_t)255;
        return p;
    };
    float* h0   = (float*)alloc((size_t)NN * 256 * 4);
    float* h1   = (float*)alloc((size_t)NN * 256 * 4);
    float* buf1 = (float*)alloc((size_t)NN * 256 * 4);
    float* buf2 = (float*)alloc((size_t)NN * 256 * 4);
    int* adjT   = (int*)alloc((size_t)NE * 4);
    int* adjP   = (int*)alloc((size_t)NE * 4);
    int* offT   = (int*)alloc((size_t)(NN + 1) * 4);
    int* offP   = (int*)alloc((size_t)(NN + 1) * 4);
    int* deg    = (int*)alloc((size_t)NN * 4);
    int* cursor = (int*)alloc((size_t)NN * 4);
    int* cntrel = (int*)alloc((size_t)2 * NN * 4);
    int* csum   = (int*)alloc(128 * 4);
    float* invT = (float*)alloc((size_t)2 * NN * 4);
    float* invP = (float*)alloc((size_t)2 * NN * 4);
    float* sums = (float*)alloc(512 * 4);
    float* ss   = (float*)alloc(512 * 4);
    int* gcnt   = (int*)alloc(64 * 4);
    int* goff   = (int*)alloc(65 * 4);

    dim3 blk(256);
    const int EB = NE / 256;               // 1250
    const int SCB = (NN + 255) / 256;      // 79
    const int nYT = (NN + 63) / 64;        // 313

    // ---- CSR build, branch t ----
    hipMemsetAsync(deg, 0, NN * 4, stream);
    hipMemsetAsync(cursor, 0, NN * 4, stream);
    hipMemsetAsync(cntrel, 0, 2 * NN * 4, stream);
    k_count_edges<<<EB, blk, 0, stream>>>(ei_t, et_t, deg, cntrel);
    k_scan_local<<<SCB, blk, 0, stream>>>(deg, offT, csum, NN);
    k_scan_csum<<<1, 128, 0, stream>>>(csum, offT + NN, SCB);
    k_scan_add<<<SCB, blk, 0, stream>>>(offT, csum, NN);
    k_fill<<<EB, blk, 0, stream>>>(ei_t, et_t, offT, cursor, adjT);
    k_invcnt<<<(2 * NN + 255) / 256, blk, 0, stream>>>(cntrel, invT);
    // ---- CSR build, branch p ----
    hipMemsetAsync(deg, 0, NN * 4, stream);
    hipMemsetAsync(cursor, 0, NN * 4, stream);
    hipMemsetAsync(cntrel, 0, 2 * NN * 4, stream);
    k_count_edges<<<EB, blk, 0, stream>>>(ei_p, et_p, deg, cntrel);
    k_scan_local<<<SCB, blk, 0, stream>>>(deg, offP, csum, NN);
    k_scan_csum<<<1, 128, 0, stream>>>(csum, offP + NN, SCB);
    k_scan_add<<<SCB, blk, 0, stream>>>(offP, csum, NN);
    k_fill<<<EB, blk, 0, stream>>>(ei_p, et_p, offP, cursor, adjP);
    k_invcnt<<<(2 * NN + 255) / 256, blk, 0, stream>>>(cntrel, invP);

    // ================= branch t =================
    // layer 1: [20000,768] -> [20000,256]
    k_gemm3<<<dim3(4, nYT, 3), blk, 0, stream>>>(x_t, 768, w_t1_root, w_t1_rel, b_t1, buf1, h0, h1, 256, NN);
    k_aggregate<256><<<(NN + 3) / 4, blk, 0, stream>>>(offT, adjT, invT, h0, h1, buf1);
    hipMemsetAsync(sums, 0, 2 * 256 * 4, stream);
    k_bnstats<<<256, blk, 0, stream>>>(buf1, sums, 256, NN);
    k_bnfinal<<<1, 256, 0, stream>>>(sums, g_t1, be_t1, ss, 256, 1.0f / NN);
    k_bnapply<<<(NN * 256 / 4 + 255) / 256, blk, 0, stream>>>(buf1, ss, 256, NN);
    // layer 2: [20000,256] -> [20000,128]
    k_gemm3<<<dim3(2, nYT, 3), blk, 0, stream>>>(buf1, 256, w_t2_root, w_t2_rel, b_t2, buf2, h0, h1, 128, NN);
    k_aggregate<128><<<(NN + 3) / 4, blk, 0, stream>>>(offT, adjT, invT, h0, h1, buf2);
    hipMemsetAsync(sums, 0, 2 * 128 * 4, stream);
    k_bnstats<<<256, blk, 0, stream>>>(buf2, sums, 128, NN);
    k_bnfinal<<<1, 128, 0, stream>>>(sums, g_t2, be_t2, ss, 128, 1.0f / NN);
    k_bnapply<<<(NN * 128 / 4 + 255) / 256, blk, 0, stream>>>(buf2, ss, 128, NN);
    // pool t
    hipMemsetAsync(gcnt, 0, 64 * 4, stream);
    k_gcnt<<<(NN + 255) / 256, blk, 0, stream>>>(bat_t, gcnt);
    k_goff<<<1, 64, 0, stream>>>(gcnt, goff);
    k_pool<<<64, 128, 0, stream>>>(buf2, goff, (float*)d_out);

    // ================= branch p =================
    // layer 1: [20000,128] -> [20000,256]
    k_gemm3<<<dim3(4, nYT, 3), blk, 0, stream>>>(x_p, 128, w_p1_root, w_p1_rel, b_p1, buf1, h0, h1, 256, NN);
    k_aggregate<256><<<(NN + 3) / 4, blk, 0, stream>>>(offP, adjP, invP, h0, h1, buf1);
    hipMemsetAsync(sums, 0, 2 * 256 * 4, stream);
    k_bnstats<<<256, blk, 0, stream>>>(buf1, sums, 256, NN);
    k_bnfinal<<<1, 256, 0, stream>>>(sums, g_p1, be_p1, ss, 256, 1.0f / NN);
    k_bnapply<<<(NN * 256 / 4 + 255) / 256, blk, 0, stream>>>(buf1, ss, 256, NN);
    // layer 2
    k_gemm3<<<dim3(2, nYT, 3), blk, 0, stream>>>(buf1, 256, w_p2_root, w_p2_rel, b_p2, buf2, h0, h1, 128, NN);
    k_aggregate<128><<<(NN + 3) / 4, blk, 0, stream>>>(offP, adjP, invP, h0, h1, buf2);
    hipMemsetAsync(sums, 0, 2 * 128 * 4, stream);
    k_bnstats<<<256, blk, 0, stream>>>(buf2, sums, 128, NN);
    k_bnfinal<<<1, 128, 0, stream>>>(sums, g_p2, be_p2, ss, 128, 1.0f / NN);
    k_bnapply<<<(NN * 128 / 4 + 255) / 256, blk, 0, stream>>>(buf2, ss, 128, NN);
    // pool p
    hipMemsetAsync(gcnt, 0, 64 * 4, stream);
    k_gcnt<<<(NN + 255) / 256, blk, 0, stream>>>(bat_p, gcnt);
    k_goff<<<1, 64, 0, stream>>>(gcnt, goff);
    k_pool<<<64, 128, 0, stream>>>(buf2, goff, (float*)d_out + 64 * 128);
}

// Round 2
// 901.807 us; speedup vs baseline: 1.5429x; 1.5429x over previous
//
#include <hip/hip_runtime.h>

#define NN 20000
#define NE 320000
#define NB 64

typedef __attribute__((ext_vector_type(4))) float f32x4;
typedef __attribute__((ext_vector_type(8))) __bf16 bf16x8;

static __device__ __forceinline__ ushort f2bf(float f) {
    uint u = __builtin_bit_cast(uint, f);
    uint r = (u + 0x7fffu + ((u >> 16) & 1u)) >> 16;
    return (ushort)r;
}
static __device__ __forceinline__ float bf2f(ushort u) {
    return __builtin_bit_cast(float, (uint)u << 16);
}

#define GLD_LDS16(g, l)                                                                     \
    __builtin_amdgcn_global_load_lds((__attribute__((address_space(1))) void*)(g),          \
                                     (__attribute__((address_space(3))) void*)(l), 16, 0, 0)

// ---------------- CSR build ----------------

__global__ __launch_bounds__(256) void k_count_edges(const int* __restrict__ ei, const int* __restrict__ et,
                                                     int* __restrict__ deg, int* __restrict__ cntrel) {
    int e = blockIdx.x * 256 + threadIdx.x;
    if (e >= NE) return;
    int dst = ei[NE + e];
    atomicAdd(&deg[dst], 1);
    atomicAdd(&cntrel[et[e] * NN + dst], 1);
}

__global__ __launch_bounds__(256) void k_scan_local(const int* __restrict__ deg, int* __restrict__ off,
                                                    int* __restrict__ csum, int n) {
    __shared__ int sh[256];
    int base = blockIdx.x * 256, tid = threadIdx.x;
    int v = (base + tid < n) ? deg[base + tid] : 0;
    sh[tid] = v; __syncthreads();
    for (int o = 1; o < 256; o <<= 1) {
        int t = (tid >= o) ? sh[tid - o] : 0;
        __syncthreads();
        sh[tid] += t;
        __syncthreads();
    }
    if (base + tid < n) off[base + tid] = sh[tid] - v;  // exclusive
    if (tid == 255) csum[blockIdx.x] = sh[255];
}

__global__ void k_scan_csum(int* __restrict__ csum, int* __restrict__ offN, int nc) {
    __shared__ int sh[128];
    int tid = threadIdx.x;
    int v = (tid < nc) ? csum[tid] : 0;
    sh[tid] = v; __syncthreads();
    for (int o = 1; o < 128; o <<= 1) {
        int t = (tid >= o) ? sh[tid - o] : 0;
        __syncthreads();
        sh[tid] += t;
        __syncthreads();
    }
    if (tid < nc) csum[tid] = sh[tid] - v;  // exclusive
    if (tid == 127) offN[0] = sh[127];      // total -> off[n]
}

__global__ __launch_bounds__(256) void k_scan_add(int* __restrict__ off, const int* __restrict__ csum, int n) {
    int i = blockIdx.x * 256 + threadIdx.x;
    if (i < n) off[i] += csum[blockIdx.x];
}

__global__ __launch_bounds__(256) void k_fill(const int* __restrict__ ei, const int* __restrict__ et,
                                              const int* __restrict__ off, int* __restrict__ cursor,
                                              int* __restrict__ adj) {
    int e = blockIdx.x * 256 + threadIdx.x;
    if (e >= NE) return;
    int src = ei[e], dst = ei[NE + e], r = et[e];
    int pos = atomicAdd(&cursor[dst], 1);
    adj[off[dst] + pos] = src | (r << 28);
}

__global__ void k_invcnt(const int* __restrict__ cntrel, float* __restrict__ inv) {
    int i = blockIdx.x * 256 + threadIdx.x;
    if (i >= 2 * NN) return;
    int c = cntrel[i];
    inv[i] = 1.0f / (float)(c > 0 ? c : 1);
}

// ---------------- casts ----------------

__global__ __launch_bounds__(256) void k_cast_x(const float* __restrict__ in, ushort* __restrict__ out, int n4) {
    int i = blockIdx.x * 256 + threadIdx.x;
    if (i >= n4) return;
    float4 v = *(const float4*)&in[(size_t)i * 4];
    ushort4 o;
    o.x = f2bf(v.x); o.y = f2bf(v.y); o.z = f2bf(v.z); o.w = f2bf(v.w);
    *(ushort4*)&out[(size_t)i * 4] = o;
}

// W [K][C] root + Wrel [2][K][C]  ->  Wt [3][C][K] bf16 (root, rel0, rel1)
__global__ __launch_bounds__(256) void k_cast_wt(const float* __restrict__ wroot, const float* __restrict__ wrel,
                                                 ushort* __restrict__ wt, int K, int C) {
    int i = blockIdx.x * 256 + threadIdx.x;
    int KC = K * C;
    if (i >= 3 * KC) return;
    int mat = i / KC, rem = i - mat * KC;
    int k = rem / C, c = rem - k * C;
    float v = (mat == 0) ? wroot[rem] : wrel[(size_t)(mat - 1) * KC + rem];
    wt[(size_t)mat * KC + (size_t)c * K + k] = f2bf(v);
}

// ---------------- MFMA GEMM: 3 products (root->fp32+bias, rel0/rel1->bf16) ----------------
// A [M,K] bf16 row-major; Wt [3][C][K] bf16 (i.e. B^T per product). 128x128 tile, 4 waves.

__global__ __launch_bounds__(256, 2) void k_gemm_mfma(const ushort* __restrict__ A, int K, int M,
                                                      const ushort* __restrict__ Wt,
                                                      const float* __restrict__ bias,
                                                      float* __restrict__ Droot, ushort* __restrict__ h0,
                                                      ushort* __restrict__ h1, int C) {
    __shared__ ushort As[128 * 64];
    __shared__ ushort Bs[128 * 64];
    int z = blockIdx.z;
    const ushort* B = Wt + (size_t)z * C * K;
    int tid = threadIdx.x;
    int lane = tid & 63, wave = tid >> 6;
    int wr = wave >> 1, wc = wave & 1;
    int rowTile = blockIdx.y * 128, colTile = blockIdx.x * 128;

    f32x4 acc[4][4] = {};

    for (int k0 = 0; k0 < K; k0 += 64) {
        __syncthreads();
#pragma unroll
        for (int i = 0; i < 4; i++) {
            int id = i * 256 + tid;
            int r = id >> 3, ck = id & 7;
            int garow = rowTile + r;
            if (garow >= M) garow = M - 1;
            GLD_LDS16(A + (size_t)garow * K + k0 + ck * 8, &As[id * 8]);
            GLD_LDS16(B + (size_t)(colTile + r) * K + k0 + ck * 8, &Bs[id * 8]);
        }
        __syncthreads();
#pragma unroll
        for (int kk = 0; kk < 2; kk++) {
            int kb = kk * 32 + (lane >> 4) * 8;
            bf16x8 af[4], bfr[4];
#pragma unroll
            for (int mi = 0; mi < 4; mi++)
                af[mi] = *(const bf16x8*)&As[(wr * 64 + mi * 16 + (lane & 15)) * 64 + kb];
#pragma unroll
            for (int ni = 0; ni < 4; ni++)
                bfr[ni] = *(const bf16x8*)&Bs[(wc * 64 + ni * 16 + (lane & 15)) * 64 + kb];
#pragma unroll
            for (int mi = 0; mi < 4; mi++)
#pragma unroll
                for (int ni = 0; ni < 4; ni++)
                    acc[mi][ni] = __builtin_amdgcn_mfma_f32_16x16x32_bf16(af[mi], bfr[ni], acc[mi][ni], 0, 0, 0);
        }
    }

    int lc = lane & 15, lr4 = (lane >> 4) * 4;
    if (z == 0) {
#pragma unroll
        for (int ni = 0; ni < 4; ni++) {
            int col = colTile + wc * 64 + ni * 16 + lc;
            float bj = bias[col];
#pragma unroll
            for (int mi = 0; mi < 4; mi++) {
#pragma unroll
                for (int j = 0; j < 4; j++) {
                    int row = rowTile + wr * 64 + mi * 16 + lr4 + j;
                    if (row < M) Droot[(size_t)row * C + col] = acc[mi][ni][j] + bj;
                }
            }
        }
    } else {
        ushort* H = (z == 1) ? h0 : h1;
#pragma unroll
        for (int ni = 0; ni < 4; ni++) {
            int col = colTile + wc * 64 + ni * 16 + lc;
#pragma unroll
            for (int mi = 0; mi < 4; mi++) {
#pragma unroll
                for (int j = 0; j < 4; j++) {
                    int row = rowTile + wr * 64 + mi * 16 + lr4 + j;
                    if (row < M) H[(size_t)row * C + col] = f2bf(acc[mi][ni][j]);
                }
            }
        }
    }
}

// ---------------- per-node mean aggregation (CSR), out += sum_r mean_r ----------------

template <int C>
__global__ __launch_bounds__(256) void k_aggregate(const int* __restrict__ off, const int* __restrict__ adj,
                                                   const float* __restrict__ inv, const ushort* __restrict__ h0,
                                                   const ushort* __restrict__ h1, float* __restrict__ out) {
    int wv = threadIdx.x >> 6, lane = threadIdx.x & 63;
    int node = blockIdx.x * 4 + wv;
    if (node >= NN) return;
    int s = off[node], e = off[node + 1];
    float w0 = inv[node], w1 = inv[NN + node];
    if (C == 256) {
        float4 acc = make_float4(0.f, 0.f, 0.f, 0.f);
        for (int i = s; i < e; i++) {
            int v = adj[i];
            int src = v & 0x0FFFFFFF, rel = v >> 28;
            const ushort* h = rel ? h1 : h0;
            float w = rel ? w1 : w0;
            ushort4 x = *(const ushort4*)&h[(size_t)src * 256 + lane * 4];
            acc.x += w * bf2f(x.x); acc.y += w * bf2f(x.y);
            acc.z += w * bf2f(x.z); acc.w += w * bf2f(x.w);
        }
        float* p = &out[(size_t)node * 256 + lane * 4];
        float4 o = *(float4*)p;
        o.x += acc.x; o.y += acc.y; o.z += acc.z; o.w += acc.w;
        *(float4*)p = o;
    } else {
        float2 acc = make_float2(0.f, 0.f);
        for (int i = s; i < e; i++) {
            int v = adj[i];
            int src = v & 0x0FFFFFFF, rel = v >> 28;
            const ushort* h = rel ? h1 : h0;
            float w = rel ? w1 : w0;
            uint x = *(const uint*)&h[(size_t)src * 128 + lane * 2];
            acc.x += w * bf2f((ushort)(x & 0xffff));
            acc.y += w * bf2f((ushort)(x >> 16));
        }
        float* p = &out[(size_t)node * 128 + lane * 2];
        float2 o = *(float2*)p;
        o.x += acc.x; o.y += acc.y;
        *(float2*)p = o;
    }
}

// ---------------- batchnorm + leaky ----------------

__global__ __launch_bounds__(256) void k_bnstats(const float* __restrict__ x, float* __restrict__ sums, int C, int M) {
    int tid = threadIdx.x;
    int groups = 256 / C;
    int col = tid & (C - 1);
    int rg = tid / C;
    float s = 0.f, s2 = 0.f;
    for (int row = blockIdx.x * groups + rg; row < M; row += gridDim.x * groups) {
        float v = x[(size_t)row * C + col];
        s += v; s2 += v * v;
    }
    atomicAdd(&sums[col], s);
    atomicAdd(&sums[C + col], s2);
}

__global__ void k_bnfinal(const float* __restrict__ sums, const float* __restrict__ g, const float* __restrict__ be,
                          float* __restrict__ ss, int C, float invM) {
    int c = threadIdx.x;
    if (c < C) {
        float mu = sums[c] * invM;
        float var = sums[C + c] * invM - mu * mu;
        float sc = g[c] * rsqrtf(var + 1e-5f);
        ss[c] = sc;
        ss[C + c] = be[c] - mu * sc;
    }
}

template <bool BF16OUT>
__global__ __launch_bounds__(256) void k_bnapply(const float* __restrict__ x, const float* __restrict__ ss,
                                                 int C, int M, float* __restrict__ outf, ushort* __restrict__ outb) {
    int i = blockIdx.x * 256 + threadIdx.x;
    int total4 = M * C / 4;
    if (i >= total4) return;
    float4 v = *(const float4*)&x[(size_t)i * 4];
    int c0 = (i * 4) & (C - 1);
    float y0 = v.x * ss[c0 + 0] + ss[C + c0 + 0];
    float y1 = v.y * ss[c0 + 1] + ss[C + c0 + 1];
    float y2 = v.z * ss[c0 + 2] + ss[C + c0 + 2];
    float y3 = v.w * ss[c0 + 3] + ss[C + c0 + 3];
    y0 = y0 >= 0.f ? y0 : 0.01f * y0;
    y1 = y1 >= 0.f ? y1 : 0.01f * y1;
    y2 = y2 >= 0.f ? y2 : 0.01f * y2;
    y3 = y3 >= 0.f ? y3 : 0.01f * y3;
    if (BF16OUT) {
        ushort4 o;
        o.x = f2bf(y0); o.y = f2bf(y1); o.z = f2bf(y2); o.w = f2bf(y3);
        *(ushort4*)&outb[(size_t)i * 4] = o;
    } else {
        float4 o = make_float4(y0, y1, y2, y3);
        *(float4*)&outf[(size_t)i * 4] = o;
    }
}

// ---------------- pooling ----------------

__global__ void k_gcnt(const int* __restrict__ batch, int* __restrict__ gcnt) {
    int n = blockIdx.x * 256 + threadIdx.x;
    if (n < NN) atomicAdd(&gcnt[batch[n]], 1);
}

__global__ void k_goff(const int* __restrict__ gcnt, int* __restrict__ goff) {
    if (threadIdx.x == 0) {
        int run = 0;
        for (int i = 0; i < NB; i++) { goff[i] = run; run += gcnt[i]; }
        goff[NB] = run;
    }
}

__global__ void k_pool(const float* __restrict__ x, const int* __restrict__ goff, float* __restrict__ out) {
    int b = blockIdx.x;
    int t = threadIdx.x;  // 128 threads = O columns
    int s = goff[b], e = goff[b + 1];
    float acc = 0.f;
    for (int r = s; r < e; r++) acc += x[(size_t)r * 128 + t];
    int cnt = e - s;
    out[b * 128 + t] = acc / (float)(cnt > 0 ? cnt : 1);
}

// ---------------- host orchestration ----------------

extern "C" void kernel_launch(void* const* d_in, const int* in_sizes, int n_in,
                              void* d_out, int out_size, void* d_ws, size_t ws_size,
                              hipStream_t stream) {
    const float* x_t = (const float*)d_in[0];
    const float* x_p = (const float*)d_in[1];
    const int* ei_t = (const int*)d_in[2];
    const int* et_t = (const int*)d_in[3];
    const int* bat_t = (const int*)d_in[4];
    const int* ei_p = (const int*)d_in[5];
    const int* et_p = (const int*)d_in[6];
    const int* bat_p = (const int*)d_in[7];
    const float* w_t1_rel = (const float*)d_in[8];
    const float* w_t1_root = (const float*)d_in[9];
    const float* b_t1 = (const float*)d_in[10];
    const float* w_t2_rel = (const float*)d_in[11];
    const float* w_t2_root = (const float*)d_in[12];
    const float* b_t2 = (const float*)d_in[13];
    const float* w_p1_rel = (const float*)d_in[14];
    const float* w_p1_root = (const float*)d_in[15];
    const float* b_p1 = (const float*)d_in[16];
    const float* w_p2_rel = (const float*)d_in[17];
    const float* w_p2_root = (const float*)d_in[18];
    const float* b_p2 = (const float*)d_in[19];
    const float* g_t1 = (const float*)d_in[20]; const float* be_t1 = (const float*)d_in[21];
    const float* g_t2 = (const float*)d_in[22]; const float* be_t2 = (const float*)d_in[23];
    const float* g_p1 = (const float*)d_in[24]; const float* be_p1 = (const float*)d_in[25];
    const float* g_p2 = (const float*)d_in[26]; const float* be_p2 = (const float*)d_in[27];

    char* wp = (char*)d_ws;
    auto alloc = [&](size_t b) -> void* {
        void* p = (void*)wp;
        wp += (b + 255) & ~(size_t)255;
        return p;
    };
    ushort* xbig = (ushort*)alloc((size_t)NN * 768 * 2);  // bf16 A; aliased as layer-1 bf16 BN output
    ushort* h0b  = (ushort*)alloc((size_t)NN * 256 * 2);
    ushort* h1b  = (ushort*)alloc((size_t)NN * 256 * 2);
    float* buf1  = (float*)alloc((size_t)NN * 256 * 4);
    float* buf2  = (float*)alloc((size_t)NN * 128 * 4);
    ushort* wtb  = (ushort*)alloc((size_t)3 * 768 * 256 * 2);
    int* adj     = (int*)alloc((size_t)NE * 4);
    int* off     = (int*)alloc((size_t)(NN + 1) * 4);
    int* deg     = (int*)alloc((size_t)NN * 4);
    int* cursor  = (int*)alloc((size_t)NN * 4);
    int* cntrel  = (int*)alloc((size_t)2 * NN * 4);
    int* csum    = (int*)alloc(128 * 4);
    float* inv   = (float*)alloc((size_t)2 * NN * 4);
    float* sums  = (float*)alloc(512 * 4);
    float* ss    = (float*)alloc(512 * 4);
    int* gcnt    = (int*)alloc(64 * 4);
    int* goff    = (int*)alloc(65 * 4);

    dim3 blk(256);
    const int EB = NE / 256;
    const int SCB = (NN + 255) / 256;
    const int nMT = (NN + 127) / 128;  // 157 row tiles

    auto build_csr = [&](const int* ei, const int* et) {
        hipMemsetAsync(deg, 0, NN * 4, stream);
        hipMemsetAsync(cursor, 0, NN * 4, stream);
        hipMemsetAsync(cntrel, 0, 2 * NN * 4, stream);
        k_count_edges<<<EB, blk, 0, stream>>>(ei, et, deg, cntrel);
        k_scan_local<<<SCB, blk, 0, stream>>>(deg, off, csum, NN);
        k_scan_csum<<<1, 128, 0, stream>>>(csum, off + NN, SCB);
        k_scan_add<<<SCB, blk, 0, stream>>>(off, csum, NN);
        k_fill<<<EB, blk, 0, stream>>>(ei, et, off, cursor, adj);
        k_invcnt<<<(2 * NN + 255) / 256, blk, 0, stream>>>(cntrel, inv);
    };

    auto run_layer = [&](const ushort* Abf, int K, const float* wroot, const float* wrel, const float* bias,
                         int C, float* buf, const float* g, const float* be,
                         bool bf16out, float* outf, ushort* outb) {
        // weights -> transposed bf16
        int wtn = 3 * K * C;
        k_cast_wt<<<(wtn + 255) / 256, blk, 0, stream>>>(wroot, wrel, wtb, K, C);
        // GEMM: root -> buf(fp32+bias), rel -> h0b/h1b (bf16)
        k_gemm_mfma<<<dim3(C / 128, nMT, 3), blk, 0, stream>>>(Abf, K, NN, wtb, bias, buf, h0b, h1b, C);
        // aggregate means into buf
        if (C == 256)
            k_aggregate<256><<<(NN + 3) / 4, blk, 0, stream>>>(off, adj, inv, h0b, h1b, buf);
        else
            k_aggregate<128><<<(NN + 3) / 4, blk, 0, stream>>>(off, adj, inv, h0b, h1b, buf);
        // BN + LeakyReLU
        hipMemsetAsync(sums, 0, 2 * C * 4, stream);
        k_bnstats<<<256, blk, 0, stream>>>(buf, sums, C, NN);
        k_bnfinal<<<1, 256, 0, stream>>>(sums, g, be, ss, C, 1.0f / NN);
        int nap = (NN * C / 4 + 255) / 256;
        if (bf16out)
            k_bnapply<true><<<nap, blk, 0, stream>>>(buf, ss, C, NN, nullptr, outb);
        else
            k_bnapply<false><<<nap, blk, 0, stream>>>(buf, ss, C, NN, outf, nullptr);
    };

    auto run_pool = [&](const int* bat, float* dst) {
        hipMemsetAsync(gcnt, 0, 64 * 4, stream);
        k_gcnt<<<(NN + 255) / 256, blk, 0, stream>>>(bat, gcnt);
        k_goff<<<1, 64, 0, stream>>>(gcnt, goff);
        k_pool<<<64, 128, 0, stream>>>(buf2, goff, dst);
    };

    // ================= branch t =================
    build_csr(ei_t, et_t);
    k_cast_x<<<(NN * 768 / 4 + 255) / 256, blk, 0, stream>>>(x_t, xbig, NN * 768 / 4);
    run_layer(xbig, 768, w_t1_root, w_t1_rel, b_t1, 256, buf1, g_t1, be_t1, true, nullptr, xbig);
    run_layer(xbig, 256, w_t2_root, w_t2_rel, b_t2, 128, buf2, g_t2, be_t2, false, buf2, nullptr);
    run_pool(bat_t, (float*)d_out);

    // ================= branch p =================
    build_csr(ei_p, et_p);
    k_cast_x<<<(NN * 128 / 4 + 255) / 256, blk, 0, stream>>>(x_p, xbig, NN * 128 / 4);
    run_layer(xbig, 128, w_p1_root, w_p1_rel, b_p1, 256, buf1, g_p1, be_p1, true, nullptr, xbig);
    run_layer(xbig, 256, w_p2_root, w_p2_rel, b_p2, 128, buf2, g_p2, be_p2, false, buf2, nullptr);
    run_pool(bat_p, (float*)d_out + 64 * 128);
}

// Round 3
// 682.738 us; speedup vs baseline: 2.0380x; 1.3209x over previous
//
#include <hip/hip_runtime.h>

#define NN 20000
#define NE 320000
#define NB 64
#define BNG 160  // bnstats partial-sum blocks

typedef __attribute__((ext_vector_type(4))) float f32x4;
typedef __attribute__((ext_vector_type(8))) __bf16 bf16x8;

static __device__ __forceinline__ ushort f2bf(float f) {
    uint u = __builtin_bit_cast(uint, f);
    uint r = (u + 0x7fffu + ((u >> 16) & 1u)) >> 16;
    return (ushort)r;
}
static __device__ __forceinline__ float bf2f(ushort u) {
    return __builtin_bit_cast(float, (uint)u << 16);
}

#define GLD_LDS16(g, l)                                                                     \
    __builtin_amdgcn_global_load_lds((__attribute__((address_space(1))) void*)(g),          \
                                     (__attribute__((address_space(3))) void*)(l), 16, 0, 0)

// ---------------- CSR build ----------------

__global__ __launch_bounds__(256) void k_count_edges(const int* __restrict__ ei, const int* __restrict__ et,
                                                     int* __restrict__ deg, int* __restrict__ cntrel) {
    int e = blockIdx.x * 256 + threadIdx.x;
    if (e >= NE) return;
    int dst = ei[NE + e];
    atomicAdd(&deg[dst], 1);
    atomicAdd(&cntrel[et[e] * NN + dst], 1);
}

__global__ __launch_bounds__(256) void k_scan_local(const int* __restrict__ deg, int* __restrict__ off,
                                                    int* __restrict__ csum, int n) {
    __shared__ int sh[256];
    int base = blockIdx.x * 256, tid = threadIdx.x;
    int v = (base + tid < n) ? deg[base + tid] : 0;
    sh[tid] = v; __syncthreads();
    for (int o = 1; o < 256; o <<= 1) {
        int t = (tid >= o) ? sh[tid - o] : 0;
        __syncthreads();
        sh[tid] += t;
        __syncthreads();
    }
    if (base + tid < n) off[base + tid] = sh[tid] - v;  // exclusive
    if (tid == 255) csum[blockIdx.x] = sh[255];
}

__global__ void k_scan_csum(int* __restrict__ csum, int* __restrict__ offN, int nc) {
    __shared__ int sh[128];
    int tid = threadIdx.x;
    int v = (tid < nc) ? csum[tid] : 0;
    sh[tid] = v; __syncthreads();
    for (int o = 1; o < 128; o <<= 1) {
        int t = (tid >= o) ? sh[tid - o] : 0;
        __syncthreads();
        sh[tid] += t;
        __syncthreads();
    }
    if (tid < nc) csum[tid] = sh[tid] - v;  // exclusive
    if (tid == 127) offN[0] = sh[127];      // total -> off[n]
}

__global__ __launch_bounds__(256) void k_scan_add(int* __restrict__ off, const int* __restrict__ csum, int n) {
    int i = blockIdx.x * 256 + threadIdx.x;
    if (i < n) off[i] += csum[blockIdx.x];
}

__global__ __launch_bounds__(256) void k_fill(const int* __restrict__ ei, const int* __restrict__ et,
                                              const int* __restrict__ off, int* __restrict__ cursor,
                                              int* __restrict__ adj) {
    int e = blockIdx.x * 256 + threadIdx.x;
    if (e >= NE) return;
    int src = ei[e], dst = ei[NE + e], r = et[e];
    int pos = atomicAdd(&cursor[dst], 1);
    adj[off[dst] + pos] = src | (r << 28);
}

__global__ void k_invcnt(const int* __restrict__ cntrel, float* __restrict__ inv) {
    int i = blockIdx.x * 256 + threadIdx.x;
    if (i >= 2 * NN) return;
    int c = cntrel[i];
    inv[i] = 1.0f / (float)(c > 0 ? c : 1);
}

// ---------------- casts ----------------

__global__ __launch_bounds__(256) void k_cast_x(const float* __restrict__ in, ushort* __restrict__ out, int n4) {
    int i = blockIdx.x * 256 + threadIdx.x;
    if (i >= n4) return;
    float4 v = *(const float4*)&in[(size_t)i * 4];
    ushort4 o;
    o.x = f2bf(v.x); o.y = f2bf(v.y); o.z = f2bf(v.z); o.w = f2bf(v.w);
    *(ushort4*)&out[(size_t)i * 4] = o;
}

// W [K][C] root + Wrel [2][K][C]  ->  Wt [3][C][K] bf16 (root, rel0, rel1)
__global__ __launch_bounds__(256) void k_cast_wt(const float* __restrict__ wroot, const float* __restrict__ wrel,
                                                 ushort* __restrict__ wt, int K, int C) {
    int i = blockIdx.x * 256 + threadIdx.x;
    int KC = K * C;
    if (i >= 3 * KC) return;
    int mat = i / KC, rem = i - mat * KC;
    int k = rem / C, c = rem - k * C;
    float v = (mat == 0) ? wroot[rem] : wrel[(size_t)(mat - 1) * KC + rem];
    wt[(size_t)mat * KC + (size_t)c * K + k] = f2bf(v);
}

// ---------------- MFMA GEMM: 3 products (root->fp32+bias, rel0/rel1->bf16) ----------------
// A [M,K] bf16 row-major; Wt [3][C][K] bf16 (i.e. B^T per product). 128x128 tile, 4 waves.

__global__ __launch_bounds__(256, 2) void k_gemm_mfma(const ushort* __restrict__ A, int K, int M,
                                                      const ushort* __restrict__ Wt,
                                                      const float* __restrict__ bias,
                                                      float* __restrict__ Droot, ushort* __restrict__ h0,
                                                      ushort* __restrict__ h1, int C) {
    __shared__ ushort As[128 * 64];
    __shared__ ushort Bs[128 * 64];
    int z = blockIdx.z;
    const ushort* B = Wt + (size_t)z * C * K;
    int tid = threadIdx.x;
    int lane = tid & 63, wave = tid >> 6;
    int wr = wave >> 1, wc = wave & 1;
    int rowTile = blockIdx.y * 128, colTile = blockIdx.x * 128;

    f32x4 acc[4][4] = {};

    for (int k0 = 0; k0 < K; k0 += 64) {
        __syncthreads();
#pragma unroll
        for (int i = 0; i < 4; i++) {
            int id = i * 256 + tid;
            int r = id >> 3, ck = id & 7;
            int garow = rowTile + r;
            if (garow >= M) garow = M - 1;
            GLD_LDS16(A + (size_t)garow * K + k0 + ck * 8, &As[id * 8]);
            GLD_LDS16(B + (size_t)(colTile + r) * K + k0 + ck * 8, &Bs[id * 8]);
        }
        __syncthreads();
#pragma unroll
        for (int kk = 0; kk < 2; kk++) {
            int kb = kk * 32 + (lane >> 4) * 8;
            bf16x8 af[4], bfr[4];
#pragma unroll
            for (int mi = 0; mi < 4; mi++)
                af[mi] = *(const bf16x8*)&As[(wr * 64 + mi * 16 + (lane & 15)) * 64 + kb];
#pragma unroll
            for (int ni = 0; ni < 4; ni++)
                bfr[ni] = *(const bf16x8*)&Bs[(wc * 64 + ni * 16 + (lane & 15)) * 64 + kb];
#pragma unroll
            for (int mi = 0; mi < 4; mi++)
#pragma unroll
                for (int ni = 0; ni < 4; ni++)
                    acc[mi][ni] = __builtin_amdgcn_mfma_f32_16x16x32_bf16(af[mi], bfr[ni], acc[mi][ni], 0, 0, 0);
        }
    }

    int lc = lane & 15, lr4 = (lane >> 4) * 4;
    if (z == 0) {
#pragma unroll
        for (int ni = 0; ni < 4; ni++) {
            int col = colTile + wc * 64 + ni * 16 + lc;
            float bj = bias[col];
#pragma unroll
            for (int mi = 0; mi < 4; mi++) {
#pragma unroll
                for (int j = 0; j < 4; j++) {
                    int row = rowTile + wr * 64 + mi * 16 + lr4 + j;
                    if (row < M) Droot[(size_t)row * C + col] = acc[mi][ni][j] + bj;
                }
            }
        }
    } else {
        ushort* H = (z == 1) ? h0 : h1;
#pragma unroll
        for (int ni = 0; ni < 4; ni++) {
            int col = colTile + wc * 64 + ni * 16 + lc;
#pragma unroll
            for (int mi = 0; mi < 4; mi++) {
#pragma unroll
                for (int j = 0; j < 4; j++) {
                    int row = rowTile + wr * 64 + mi * 16 + lr4 + j;
                    if (row < M) H[(size_t)row * C + col] = f2bf(acc[mi][ni][j]);
                }
            }
        }
    }
}

// ---------------- per-node mean aggregation (CSR), out += sum_r mean_r ----------------

template <int C>
__global__ __launch_bounds__(256) void k_aggregate(const int* __restrict__ off, const int* __restrict__ adj,
                                                   const float* __restrict__ inv, const ushort* __restrict__ h0,
                                                   const ushort* __restrict__ h1, float* __restrict__ out) {
    int wv = threadIdx.x >> 6, lane = threadIdx.x & 63;
    int node = blockIdx.x * 4 + wv;
    if (node >= NN) return;
    int s = off[node], e = off[node + 1];
    float w0 = inv[node], w1 = inv[NN + node];
    if (C == 256) {
        float4 acc = make_float4(0.f, 0.f, 0.f, 0.f);
        for (int i = s; i < e; i++) {
            int v = adj[i];
            int src = v & 0x0FFFFFFF, rel = v >> 28;
            const ushort* h = rel ? h1 : h0;
            float w = rel ? w1 : w0;
            ushort4 x = *(const ushort4*)&h[(size_t)src * 256 + lane * 4];
            acc.x += w * bf2f(x.x); acc.y += w * bf2f(x.y);
            acc.z += w * bf2f(x.z); acc.w += w * bf2f(x.w);
        }
        float* p = &out[(size_t)node * 256 + lane * 4];
        float4 o = *(float4*)p;
        o.x += acc.x; o.y += acc.y; o.z += acc.z; o.w += acc.w;
        *(float4*)p = o;
    } else {
        float2 acc = make_float2(0.f, 0.f);
        for (int i = s; i < e; i++) {
            int v = adj[i];
            int src = v & 0x0FFFFFFF, rel = v >> 28;
            const ushort* h = rel ? h1 : h0;
            float w = rel ? w1 : w0;
            uint x = *(const uint*)&h[(size_t)src * 128 + lane * 2];
            acc.x += w * bf2f((ushort)(x & 0xffff));
            acc.y += w * bf2f((ushort)(x >> 16));
        }
        float* p = &out[(size_t)node * 128 + lane * 2];
        float2 o = *(float2*)p;
        o.x += acc.x; o.y += acc.y;
        *(float2*)p = o;
    }
}

// ---------------- batchnorm + leaky (atomic-free two-stage stats) ----------------

// stage 1: per-block partial sums -> part[blk][0..C)=sum, part[blk][C..2C)=sumsq
__global__ __launch_bounds__(256) void k_bnstats(const float* __restrict__ x, float* __restrict__ part,
                                                 int C, int M) {
    int tid = threadIdx.x;
    int groups = 256 / C;  // 1 (C=256) or 2 (C=128)
    int col = tid & (C - 1);
    int rg = tid / C;
    float s = 0.f, s2 = 0.f;
    for (int row = blockIdx.x * groups + rg; row < M; row += BNG * groups) {
        float v = x[(size_t)row * C + col];
        s += v; s2 += v * v;
    }
    __shared__ float shs[256], shq[256];
    shs[tid] = s; shq[tid] = s2;
    __syncthreads();
    if (tid < C) {
        for (int g = 1; g < groups; g++) { shs[tid] += shs[tid + g * C]; shq[tid] += shq[tid + g * C]; }
        part[(size_t)blockIdx.x * 2 * C + tid] = shs[tid];
        part[(size_t)blockIdx.x * 2 * C + C + tid] = shq[tid];
    }
}

// stage 2: reduce partials + compute scale/shift
__global__ void k_bnreduce(const float* __restrict__ part, const float* __restrict__ g,
                           const float* __restrict__ be, float* __restrict__ ss, int C, float invM) {
    int c = threadIdx.x;
    if (c >= C) return;
    float s = 0.f, s2 = 0.f;
    for (int b = 0; b < BNG; b++) {
        s += part[(size_t)b * 2 * C + c];
        s2 += part[(size_t)b * 2 * C + C + c];
    }
    float mu = s * invM;
    float var = s2 * invM - mu * mu;
    float sc = g[c] * rsqrtf(var + 1e-5f);
    ss[c] = sc;
    ss[C + c] = be[c] - mu * sc;
}

template <bool BF16OUT>
__global__ __launch_bounds__(256) void k_bnapply(const float* __restrict__ x, const float* __restrict__ ss,
                                                 int C, int M, float* __restrict__ outf, ushort* __restrict__ outb) {
    int i = blockIdx.x * 256 + threadIdx.x;
    int total4 = M * C / 4;
    if (i >= total4) return;
    float4 v = *(const float4*)&x[(size_t)i * 4];
    int c0 = (i * 4) & (C - 1);
    float y0 = v.x * ss[c0 + 0] + ss[C + c0 + 0];
    float y1 = v.y * ss[c0 + 1] + ss[C + c0 + 1];
    float y2 = v.z * ss[c0 + 2] + ss[C + c0 + 2];
    float y3 = v.w * ss[c0 + 3] + ss[C + c0 + 3];
    y0 = y0 >= 0.f ? y0 : 0.01f * y0;
    y1 = y1 >= 0.f ? y1 : 0.01f * y1;
    y2 = y2 >= 0.f ? y2 : 0.01f * y2;
    y3 = y3 >= 0.f ? y3 : 0.01f * y3;
    if (BF16OUT) {
        ushort4 o;
        o.x = f2bf(y0); o.y = f2bf(y1); o.z = f2bf(y2); o.w = f2bf(y3);
        *(ushort4*)&outb[(size_t)i * 4] = o;
    } else {
        float4 o = make_float4(y0, y1, y2, y3);
        *(float4*)&outf[(size_t)i * 4] = o;
    }
}

// ---------------- pooling ----------------

// batch is sorted: goff[b] = lower_bound(batch, b); 65 threads
__global__ void k_goff_bs(const int* __restrict__ batch, int* __restrict__ goff) {
    int b = threadIdx.x;
    if (b > NB) return;
    int lo = 0, hi = NN;
    while (lo < hi) {
        int mid = (lo + hi) >> 1;
        if (batch[mid] < b) lo = mid + 1; else hi = mid;
    }
    goff[b] = lo;
}

__global__ __launch_bounds__(256) void k_pool(const float* __restrict__ x, const int* __restrict__ goff,
                                              float* __restrict__ out) {
    int b = blockIdx.x;
    int t = threadIdx.x & 127, rg = threadIdx.x >> 7;  // 2 row groups x 128 cols
    __shared__ float sh[256];
    int s = goff[b], e = goff[b + 1];
    float acc = 0.f;
    for (int r = s + rg; r < e; r += 2) acc += x[(size_t)r * 128 + t];
    sh[threadIdx.x] = acc;
    __syncthreads();
    if (rg == 0) {
        float v = sh[t] + sh[128 + t];
        int cnt = e - s;
        out[b * 128 + t] = v / (float)(cnt > 0 ? cnt : 1);
    }
}

// ---------------- host orchestration ----------------

extern "C" void kernel_launch(void* const* d_in, const int* in_sizes, int n_in,
                              void* d_out, int out_size, void* d_ws, size_t ws_size,
                              hipStream_t stream) {
    const float* x_t = (const float*)d_in[0];
    const float* x_p = (const float*)d_in[1];
    const int* ei_t = (const int*)d_in[2];
    const int* et_t = (const int*)d_in[3];
    const int* bat_t = (const int*)d_in[4];
    const int* ei_p = (const int*)d_in[5];
    const int* et_p = (const int*)d_in[6];
    const int* bat_p = (const int*)d_in[7];
    const float* w_t1_rel = (const float*)d_in[8];
    const float* w_t1_root = (const float*)d_in[9];
    const float* b_t1 = (const float*)d_in[10];
    const float* w_t2_rel = (const float*)d_in[11];
    const float* w_t2_root = (const float*)d_in[12];
    const float* b_t2 = (const float*)d_in[13];
    const float* w_p1_rel = (const float*)d_in[14];
    const float* w_p1_root = (const float*)d_in[15];
    const float* b_p1 = (const float*)d_in[16];
    const float* w_p2_rel = (const float*)d_in[17];
    const float* w_p2_root = (const float*)d_in[18];
    const float* b_p2 = (const float*)d_in[19];
    const float* g_t1 = (const float*)d_in[20]; const float* be_t1 = (const float*)d_in[21];
    const float* g_t2 = (const float*)d_in[22]; const float* be_t2 = (const float*)d_in[23];
    const float* g_p1 = (const float*)d_in[24]; const float* be_p1 = (const float*)d_in[25];
    const float* g_p2 = (const float*)d_in[26]; const float* be_p2 = (const float*)d_in[27];

    char* wp = (char*)d_ws;
    auto alloc = [&](size_t b) -> void* {
        void* p = (void*)wp;
        wp += (b + 255) & ~(size_t)255;
        return p;
    };
    ushort* xbig = (ushort*)alloc((size_t)NN * 768 * 2);  // bf16 A; aliased as layer-1 bf16 BN output
    ushort* h0b  = (ushort*)alloc((size_t)NN * 256 * 2);
    ushort* h1b  = (ushort*)alloc((size_t)NN * 256 * 2);
    float* buf1  = (float*)alloc((size_t)NN * 256 * 4);
    float* buf2  = (float*)alloc((size_t)NN * 128 * 4);
    ushort* wtb  = (ushort*)alloc((size_t)3 * 768 * 256 * 2);
    int* adj     = (int*)alloc((size_t)NE * 4);
    int* off     = (int*)alloc((size_t)(NN + 1) * 4);
    int* deg     = (int*)alloc((size_t)NN * 4);
    int* cursor  = (int*)alloc((size_t)NN * 4);
    int* cntrel  = (int*)alloc((size_t)2 * NN * 4);
    int* csum    = (int*)alloc(128 * 4);
    float* inv   = (float*)alloc((size_t)2 * NN * 4);
    float* part  = (float*)alloc((size_t)BNG * 512 * 4);
    float* ss    = (float*)alloc(512 * 4);
    int* goff    = (int*)alloc(65 * 4);

    dim3 blk(256);
    const int EB = NE / 256;
    const int SCB = (NN + 255) / 256;
    const int nMT = (NN + 127) / 128;  // 157 row tiles

    auto build_csr = [&](const int* ei, const int* et) {
        hipMemsetAsync(deg, 0, NN * 4, stream);
        hipMemsetAsync(cursor, 0, NN * 4, stream);
        hipMemsetAsync(cntrel, 0, 2 * NN * 4, stream);
        k_count_edges<<<EB, blk, 0, stream>>>(ei, et, deg, cntrel);
        k_scan_local<<<SCB, blk, 0, stream>>>(deg, off, csum, NN);
        k_scan_csum<<<1, 128, 0, stream>>>(csum, off + NN, SCB);
        k_scan_add<<<SCB, blk, 0, stream>>>(off, csum, NN);
        k_fill<<<EB, blk, 0, stream>>>(ei, et, off, cursor, adj);
        k_invcnt<<<(2 * NN + 255) / 256, blk, 0, stream>>>(cntrel, inv);
    };

    auto run_layer = [&](const ushort* Abf, int K, const float* wroot, const float* wrel, const float* bias,
                         int C, float* buf, const float* g, const float* be,
                         bool bf16out, float* outf, ushort* outb) {
        int wtn = 3 * K * C;
        k_cast_wt<<<(wtn + 255) / 256, blk, 0, stream>>>(wroot, wrel, wtb, K, C);
        k_gemm_mfma<<<dim3(C / 128, nMT, 3), blk, 0, stream>>>(Abf, K, NN, wtb, bias, buf, h0b, h1b, C);
        if (C == 256)
            k_aggregate<256><<<(NN + 3) / 4, blk, 0, stream>>>(off, adj, inv, h0b, h1b, buf);
        else
            k_aggregate<128><<<(NN + 3) / 4, blk, 0, stream>>>(off, adj, inv, h0b, h1b, buf);
        k_bnstats<<<BNG, blk, 0, stream>>>(buf, part, C, NN);
        k_bnreduce<<<1, 256, 0, stream>>>(part, g, be, ss, C, 1.0f / NN);
        int nap = (NN * C / 4 + 255) / 256;
        if (bf16out)
            k_bnapply<true><<<nap, blk, 0, stream>>>(buf, ss, C, NN, nullptr, outb);
        else
            k_bnapply<false><<<nap, blk, 0, stream>>>(buf, ss, C, NN, outf, nullptr);
    };

    // ================= branch t =================
    build_csr(ei_t, et_t);
    k_cast_x<<<(NN * 768 / 4 + 255) / 256, blk, 0, stream>>>(x_t, xbig, NN * 768 / 4);
    run_layer(xbig, 768, w_t1_root, w_t1_rel, b_t1, 256, buf1, g_t1, be_t1, true, nullptr, xbig);
    run_layer(xbig, 256, w_t2_root, w_t2_rel, b_t2, 128, buf2, g_t2, be_t2, false, buf2, nullptr);
    k_goff_bs<<<1, 128, 0, stream>>>(bat_t, goff);
    k_pool<<<64, blk, 0, stream>>>(buf2, goff, (float*)d_out);

    // ================= branch p =================
    build_csr(ei_p, et_p);
    k_cast_x<<<(NN * 128 / 4 + 255) / 256, blk, 0, stream>>>(x_p, xbig, NN * 128 / 4);
    run_layer(xbig, 128, w_p1_root, w_p1_rel, b_p1, 256, buf1, g_p1, be_p1, true, nullptr, xbig);
    run_layer(xbig, 256, w_p2_root, w_p2_rel, b_p2, 128, buf2, g_p2, be_p2, false, buf2, nullptr);
    k_goff_bs<<<1, 128, 0, stream>>>(bat_p, goff);
    k_pool<<<64, blk, 0, stream>>>(buf2, goff, (float*)d_out + 64 * 128);
}

// Round 4
// 571.298 us; speedup vs baseline: 2.4355x; 1.1951x over previous
//
#include <hip/hip_runtime.h>

#define NN 20000
#define NE 320000
#define NB 64
#define BNG 128  // bnstats partial-sum blocks

typedef __attribute__((ext_vector_type(4))) float f32x4;
typedef __attribute__((ext_vector_type(8))) __bf16 bf16x8;

static __device__ __forceinline__ ushort f2bf(float f) {
    uint u = __builtin_bit_cast(uint, f);
    uint r = (u + 0x7fffu + ((u >> 16) & 1u)) >> 16;
    return (ushort)r;
}
static __device__ __forceinline__ float bf2f(ushort u) {
    return __builtin_bit_cast(float, (uint)u << 16);
}

#define GLD_LDS16(g, l)                                                                     \
    __builtin_amdgcn_global_load_lds((__attribute__((address_space(1))) void*)(g),          \
                                     (__attribute__((address_space(3))) void*)(l), 16, 0, 0)

// ---------------- CSR build ----------------

__global__ __launch_bounds__(256) void k_count_edges(const int* __restrict__ ei, const int* __restrict__ et,
                                                     int* __restrict__ deg, int* __restrict__ cntrel) {
    int e = blockIdx.x * 256 + threadIdx.x;
    if (e >= NE) return;
    int dst = ei[NE + e];
    atomicAdd(&deg[dst], 1);
    atomicAdd(&cntrel[et[e] * NN + dst], 1);
}

__global__ __launch_bounds__(256) void k_scan_local(const int* __restrict__ deg, int* __restrict__ off,
                                                    int* __restrict__ csum, int n) {
    __shared__ int sh[256];
    int base = blockIdx.x * 256, tid = threadIdx.x;
    int v = (base + tid < n) ? deg[base + tid] : 0;
    sh[tid] = v; __syncthreads();
    for (int o = 1; o < 256; o <<= 1) {
        int t = (tid >= o) ? sh[tid - o] : 0;
        __syncthreads();
        sh[tid] += t;
        __syncthreads();
    }
    if (base + tid < n) off[base + tid] = sh[tid] - v;  // exclusive
    if (tid == 255) csum[blockIdx.x] = sh[255];
}

__global__ void k_scan_csum(int* __restrict__ csum, int* __restrict__ offN, int nc) {
    __shared__ int sh[128];
    int tid = threadIdx.x;
    int v = (tid < nc) ? csum[tid] : 0;
    sh[tid] = v; __syncthreads();
    for (int o = 1; o < 128; o <<= 1) {
        int t = (tid >= o) ? sh[tid - o] : 0;
        __syncthreads();
        sh[tid] += t;
        __syncthreads();
    }
    if (tid < nc) csum[tid] = sh[tid] - v;  // exclusive
    if (tid == 127) offN[0] = sh[127];      // total -> off[n]
}

__global__ __launch_bounds__(256) void k_scan_add(int* __restrict__ off, const int* __restrict__ csum, int n) {
    int i = blockIdx.x * 256 + threadIdx.x;
    if (i < n) off[i] += csum[blockIdx.x];
}

__global__ __launch_bounds__(256) void k_fill(const int* __restrict__ ei, const int* __restrict__ et,
                                              const int* __restrict__ off, int* __restrict__ cursor,
                                              int* __restrict__ adj) {
    int e = blockIdx.x * 256 + threadIdx.x;
    if (e >= NE) return;
    int src = ei[e], dst = ei[NE + e], r = et[e];
    int pos = atomicAdd(&cursor[dst], 1);
    adj[off[dst] + pos] = src | (r << 28);
}

__global__ void k_invcnt(const int* __restrict__ cntrel, float* __restrict__ inv) {
    int i = blockIdx.x * 256 + threadIdx.x;
    if (i >= 2 * NN) return;
    int c = cntrel[i];
    inv[i] = 1.0f / (float)(c > 0 ? c : 1);
}

// ---------------- casts ----------------

__global__ __launch_bounds__(256) void k_cast_x(const float* __restrict__ in, ushort* __restrict__ out, int n4) {
    int i = blockIdx.x * 256 + threadIdx.x;
    if (i >= n4) return;
    float4 v = *(const float4*)&in[(size_t)i * 4];
    ushort4 o;
    o.x = f2bf(v.x); o.y = f2bf(v.y); o.z = f2bf(v.z); o.w = f2bf(v.w);
    *(ushort4*)&out[(size_t)i * 4] = o;
}

// W [K][C] (root / rel0 / rel1) -> Wt [3][C][K] bf16, 32x32 LDS tile transpose
__global__ __launch_bounds__(256) void k_cast_wtT(const float* __restrict__ wroot, const float* __restrict__ wrel,
                                                  ushort* __restrict__ wt, int K, int C) {
    __shared__ float tile[32][33];
    int mat = blockIdx.z;
    int KC = K * C;
    const float* W = (mat == 0) ? wroot : wrel + (size_t)(mat - 1) * KC;
    int k0 = blockIdx.x * 32, c0 = blockIdx.y * 32;
    int tx = threadIdx.x & 31, ty = threadIdx.x >> 5;  // 32 x 8
#pragma unroll
    for (int i = 0; i < 4; i++)
        tile[ty + i * 8][tx] = W[(size_t)(k0 + ty + i * 8) * C + c0 + tx];
    __syncthreads();
#pragma unroll
    for (int i = 0; i < 4; i++)
        wt[(size_t)mat * KC + (size_t)(c0 + ty + i * 8) * K + k0 + tx] = f2bf(tile[tx][ty + i * 8]);
}

// ---------------- MFMA GEMM: 3 products (root->fp32+bias, rel0/rel1->bf16) ----------------
// A [M,K] bf16 row-major; Wt [3][C][K] bf16 (B^T per product). 128x128 tile, 4 waves.
// 1-D grid with bijective XCD-chunked swizzle, y-major: each XCD owns a contiguous
// band of row panels; the (x,z) blocks sharing an A-panel are adjacent in time.

__global__ __launch_bounds__(256, 4) void k_gemm_mfma(const ushort* __restrict__ A, int K, int M,
                                                      const ushort* __restrict__ Wt,
                                                      const float* __restrict__ bias,
                                                      float* __restrict__ Droot, ushort* __restrict__ h0,
                                                      ushort* __restrict__ h1, int C) {
    __shared__ ushort As[128 * 64];
    __shared__ ushort Bs[128 * 64];

    int nx = C >> 7;                 // col tiles
    int perY = nx * 3;
    int nwg = gridDim.x;
    int orig = blockIdx.x;
    int q = nwg >> 3, r = nwg & 7;
    int xcd = orig & 7, pos = orig >> 3;
    int wgid = (xcd < r) ? (xcd * (q + 1) + pos) : (r * (q + 1) + (xcd - r) * q + pos);
    int y = wgid / perY, rem = wgid - y * perY;
    int x = rem / 3, z = rem - x * 3;

    const ushort* B = Wt + (size_t)z * C * K;
    int tid = threadIdx.x;
    int lane = tid & 63, wave = tid >> 6;
    int wr = wave >> 1, wc = wave & 1;
    int rowTile = y * 128, colTile = x * 128;

    f32x4 acc[4][4] = {};

    for (int k0 = 0; k0 < K; k0 += 64) {
        __syncthreads();
#pragma unroll
        for (int i = 0; i < 4; i++) {
            int id = i * 256 + tid;
            int rr = id >> 3, ck = id & 7;
            int garow = rowTile + rr;
            if (garow >= M) garow = M - 1;
            GLD_LDS16(A + (size_t)garow * K + k0 + ck * 8, &As[id * 8]);
            GLD_LDS16(B + (size_t)(colTile + rr) * K + k0 + ck * 8, &Bs[id * 8]);
        }
        __syncthreads();
#pragma unroll
        for (int kk = 0; kk < 2; kk++) {
            int kb = kk * 32 + (lane >> 4) * 8;
            bf16x8 af[4], bfr[4];
#pragma unroll
            for (int mi = 0; mi < 4; mi++)
                af[mi] = *(const bf16x8*)&As[(wr * 64 + mi * 16 + (lane & 15)) * 64 + kb];
#pragma unroll
            for (int ni = 0; ni < 4; ni++)
                bfr[ni] = *(const bf16x8*)&Bs[(wc * 64 + ni * 16 + (lane & 15)) * 64 + kb];
#pragma unroll
            for (int mi = 0; mi < 4; mi++)
#pragma unroll
                for (int ni = 0; ni < 4; ni++)
                    acc[mi][ni] = __builtin_amdgcn_mfma_f32_16x16x32_bf16(af[mi], bfr[ni], acc[mi][ni], 0, 0, 0);
        }
    }

    int lc = lane & 15, lr4 = (lane >> 4) * 4;
    if (z == 0) {
#pragma unroll
        for (int ni = 0; ni < 4; ni++) {
            int col = colTile + wc * 64 + ni * 16 + lc;
            float bj = bias[col];
#pragma unroll
            for (int mi = 0; mi < 4; mi++) {
#pragma unroll
                for (int j = 0; j < 4; j++) {
                    int row = rowTile + wr * 64 + mi * 16 + lr4 + j;
                    if (row < M) Droot[(size_t)row * C + col] = acc[mi][ni][j] + bj;
                }
            }
        }
    } else {
        ushort* H = (z == 1) ? h0 : h1;
#pragma unroll
        for (int ni = 0; ni < 4; ni++) {
            int col = colTile + wc * 64 + ni * 16 + lc;
#pragma unroll
            for (int mi = 0; mi < 4; mi++) {
#pragma unroll
                for (int j = 0; j < 4; j++) {
                    int row = rowTile + wr * 64 + mi * 16 + lr4 + j;
                    if (row < M) H[(size_t)row * C + col] = f2bf(acc[mi][ni][j]);
                }
            }
        }
    }
}

// ---------------- per-node mean aggregation (CSR), out += sum_r mean_r ----------------
// 2-way unrolled edge loop: two independent gather chains in flight.

template <int C>
__global__ __launch_bounds__(256) void k_aggregate(const int* __restrict__ off, const int* __restrict__ adj,
                                                   const float* __restrict__ inv, const ushort* __restrict__ h0,
                                                   const ushort* __restrict__ h1, float* __restrict__ out) {
    int wv = threadIdx.x >> 6, lane = threadIdx.x & 63;
    int node = blockIdx.x * 4 + wv;
    if (node >= NN) return;
    int s = off[node], e = off[node + 1];
    float w0 = inv[node], w1 = inv[NN + node];
    if (C == 256) {
        float4 a0 = make_float4(0.f, 0.f, 0.f, 0.f);
        float4 a1 = make_float4(0.f, 0.f, 0.f, 0.f);
        int i = s;
        for (; i + 1 < e; i += 2) {
            int v0 = adj[i], v1 = adj[i + 1];
            int s0 = v0 & 0x0FFFFFFF, r0 = v0 >> 28;
            int s1 = v1 & 0x0FFFFFFF, r1 = v1 >> 28;
            const ushort* hp0 = r0 ? h1 : h0; float wt0 = r0 ? w1 : w0;
            const ushort* hp1 = r1 ? h1 : h0; float wt1 = r1 ? w1 : w0;
            ushort4 x0 = *(const ushort4*)&hp0[(size_t)s0 * 256 + lane * 4];
            ushort4 x1 = *(const ushort4*)&hp1[(size_t)s1 * 256 + lane * 4];
            a0.x += wt0 * bf2f(x0.x); a0.y += wt0 * bf2f(x0.y);
            a0.z += wt0 * bf2f(x0.z); a0.w += wt0 * bf2f(x0.w);
            a1.x += wt1 * bf2f(x1.x); a1.y += wt1 * bf2f(x1.y);
            a1.z += wt1 * bf2f(x1.z); a1.w += wt1 * bf2f(x1.w);
        }
        if (i < e) {
            int v0 = adj[i];
            int s0 = v0 & 0x0FFFFFFF, r0 = v0 >> 28;
            const ushort* hp0 = r0 ? h1 : h0; float wt0 = r0 ? w1 : w0;
            ushort4 x0 = *(const ushort4*)&hp0[(size_t)s0 * 256 + lane * 4];
            a0.x += wt0 * bf2f(x0.x); a0.y += wt0 * bf2f(x0.y);
            a0.z += wt0 * bf2f(x0.z); a0.w += wt0 * bf2f(x0.w);
        }
        float* p = &out[(size_t)node * 256 + lane * 4];
        float4 o = *(float4*)p;
        o.x += a0.x + a1.x; o.y += a0.y + a1.y; o.z += a0.z + a1.z; o.w += a0.w + a1.w;
        *(float4*)p = o;
    } else {
        float2 a0 = make_float2(0.f, 0.f);
        float2 a1 = make_float2(0.f, 0.f);
        int i = s;
        for (; i + 1 < e; i += 2) {
            int v0 = adj[i], v1 = adj[i + 1];
            int s0 = v0 & 0x0FFFFFFF, r0 = v0 >> 28;
            int s1 = v1 & 0x0FFFFFFF, r1 = v1 >> 28;
            const ushort* hp0 = r0 ? h1 : h0; float wt0 = r0 ? w1 : w0;
            const ushort* hp1 = r1 ? h1 : h0; float wt1 = r1 ? w1 : w0;
            uint x0 = *(const uint*)&hp0[(size_t)s0 * 128 + lane * 2];
            uint x1 = *(const uint*)&hp1[(size_t)s1 * 128 + lane * 2];
            a0.x += wt0 * bf2f((ushort)(x0 & 0xffff)); a0.y += wt0 * bf2f((ushort)(x0 >> 16));
            a1.x += wt1 * bf2f((ushort)(x1 & 0xffff)); a1.y += wt1 * bf2f((ushort)(x1 >> 16));
        }
        if (i < e) {
            int v0 = adj[i];
            int s0 = v0 & 0x0FFFFFFF, r0 = v0 >> 28;
            const ushort* hp0 = r0 ? h1 : h0; float wt0 = r0 ? w1 : w0;
            uint x0 = *(const uint*)&hp0[(size_t)s0 * 128 + lane * 2];
            a0.x += wt0 * bf2f((ushort)(x0 & 0xffff)); a0.y += wt0 * bf2f((ushort)(x0 >> 16));
        }
        float* p = &out[(size_t)node * 128 + lane * 2];
        float2 o = *(float2*)p;
        o.x += a0.x + a1.x; o.y += a0.y + a1.y;
        *(float2*)p = o;
    }
}

// ---------------- batchnorm + leaky (atomic-free two-stage stats) ----------------

// stage 1: partials, transposed layout part[c][b] (c in [0,2C), b in [0,BNG))
__global__ __launch_bounds__(256) void k_bnstats(const float* __restrict__ x, float* __restrict__ part,
                                                 int C, int M) {
    int tid = threadIdx.x;
    int groups = 256 / C;  // 1 (C=256) or 2 (C=128)
    int col = tid & (C - 1);
    int rg = tid / C;
    float s = 0.f, s2 = 0.f;
    for (int row = blockIdx.x * groups + rg; row < M; row += BNG * groups) {
        float v = x[(size_t)row * C + col];
        s += v; s2 += v * v;
    }
    __shared__ float shs[256], shq[256];
    shs[tid] = s; shq[tid] = s2;
    __syncthreads();
    if (tid < C) {
        for (int g = 1; g < groups; g++) { shs[tid] += shs[tid + g * C]; shq[tid] += shq[tid + g * C]; }
        part[(size_t)tid * BNG + blockIdx.x] = shs[tid];
        part[(size_t)(C + tid) * BNG + blockIdx.x] = shq[tid];
    }
}

// stage 2: wave per column; reduce BNG partials, compute scale/shift
__global__ __launch_bounds__(256) void k_bnreduce(const float* __restrict__ part, const float* __restrict__ g,
                                                  const float* __restrict__ be, float* __restrict__ ss,
                                                  int C, float invM) {
    int wv = threadIdx.x >> 6, lane = threadIdx.x & 63;
    int c = blockIdx.x * 4 + wv;
    if (c >= C) return;
    float s = part[(size_t)c * BNG + lane] + part[(size_t)c * BNG + 64 + lane];
    float s2 = part[(size_t)(C + c) * BNG + lane] + part[(size_t)(C + c) * BNG + 64 + lane];
#pragma unroll
    for (int o = 32; o >= 1; o >>= 1) {
        s += __shfl_xor(s, o, 64);
        s2 += __shfl_xor(s2, o, 64);
    }
    if (lane == 0) {
        float mu = s * invM;
        float var = s2 * invM - mu * mu;
        float sc = g[c] * rsqrtf(var + 1e-5f);
        ss[c] = sc;
        ss[C + c] = be[c] - mu * sc;
    }
}

template <bool BF16OUT>
__global__ __launch_bounds__(256) void k_bnapply(const float* __restrict__ x, const float* __restrict__ ss,
                                                 int C, int M, float* __restrict__ outf, ushort* __restrict__ outb) {
    int i = blockIdx.x * 256 + threadIdx.x;
    int total4 = M * C / 4;
    if (i >= total4) return;
    float4 v = *(const float4*)&x[(size_t)i * 4];
    int c0 = (i * 4) & (C - 1);
    float y0 = v.x * ss[c0 + 0] + ss[C + c0 + 0];
    float y1 = v.y * ss[c0 + 1] + ss[C + c0 + 1];
    float y2 = v.z * ss[c0 + 2] + ss[C + c0 + 2];
    float y3 = v.w * ss[c0 + 3] + ss[C + c0 + 3];
    y0 = y0 >= 0.f ? y0 : 0.01f * y0;
    y1 = y1 >= 0.f ? y1 : 0.01f * y1;
    y2 = y2 >= 0.f ? y2 : 0.01f * y2;
    y3 = y3 >= 0.f ? y3 : 0.01f * y3;
    if (BF16OUT) {
        ushort4 o;
        o.x = f2bf(y0); o.y = f2bf(y1); o.z = f2bf(y2); o.w = f2bf(y3);
        *(ushort4*)&outb[(size_t)i * 4] = o;
    } else {
        float4 o = make_float4(y0, y1, y2, y3);
        *(float4*)&outf[(size_t)i * 4] = o;
    }
}

// ---------------- pooling ----------------

// batch is sorted: goff[b] = lower_bound(batch, b)
__global__ void k_goff_bs(const int* __restrict__ batch, int* __restrict__ goff) {
    int b = threadIdx.x;
    if (b > NB) return;
    int lo = 0, hi = NN;
    while (lo < hi) {
        int mid = (lo + hi) >> 1;
        if (batch[mid] < b) lo = mid + 1; else hi = mid;
    }
    goff[b] = lo;
}

__global__ __launch_bounds__(512) void k_pool(const float* __restrict__ x, const int* __restrict__ goff,
                                              float* __restrict__ out) {
    int b = blockIdx.x;
    int t = threadIdx.x & 127, rg = threadIdx.x >> 7;  // 4 row groups x 128 cols
    __shared__ float sh[512];
    int s = goff[b], e = goff[b + 1];
    float acc = 0.f;
    for (int r = s + rg; r < e; r += 4) acc += x[(size_t)r * 128 + t];
    sh[threadIdx.x] = acc;
    __syncthreads();
    if (rg == 0) {
        float v = sh[t] + sh[128 + t] + sh[256 + t] + sh[384 + t];
        int cnt = e - s;
        out[b * 128 + t] = v / (float)(cnt > 0 ? cnt : 1);
    }
}

// ---------------- host orchestration ----------------

extern "C" void kernel_launch(void* const* d_in, const int* in_sizes, int n_in,
                              void* d_out, int out_size, void* d_ws, size_t ws_size,
                              hipStream_t stream) {
    const float* x_t = (const float*)d_in[0];
    const float* x_p = (const float*)d_in[1];
    const int* ei_t = (const int*)d_in[2];
    const int* et_t = (const int*)d_in[3];
    const int* bat_t = (const int*)d_in[4];
    const int* ei_p = (const int*)d_in[5];
    const int* et_p = (const int*)d_in[6];
    const int* bat_p = (const int*)d_in[7];
    const float* w_t1_rel = (const float*)d_in[8];
    const float* w_t1_root = (const float*)d_in[9];
    const float* b_t1 = (const float*)d_in[10];
    const float* w_t2_rel = (const float*)d_in[11];
    const float* w_t2_root = (const float*)d_in[12];
    const float* b_t2 = (const float*)d_in[13];
    const float* w_p1_rel = (const float*)d_in[14];
    const float* w_p1_root = (const float*)d_in[15];
    const float* b_p1 = (const float*)d_in[16];
    const float* w_p2_rel = (const float*)d_in[17];
    const float* w_p2_root = (const float*)d_in[18];
    const float* b_p2 = (const float*)d_in[19];
    const float* g_t1 = (const float*)d_in[20]; const float* be_t1 = (const float*)d_in[21];
    const float* g_t2 = (const float*)d_in[22]; const float* be_t2 = (const float*)d_in[23];
    const float* g_p1 = (const float*)d_in[24]; const float* be_p1 = (const float*)d_in[25];
    const float* g_p2 = (const float*)d_in[26]; const float* be_p2 = (const float*)d_in[27];

    char* wp = (char*)d_ws;
    auto alloc = [&](size_t b) -> void* {
        void* p = (void*)wp;
        wp += (b + 255) & ~(size_t)255;
        return p;
    };
    ushort* xbig = (ushort*)alloc((size_t)NN * 768 * 2);  // bf16 A; aliased as layer-1 bf16 BN output
    ushort* h0b  = (ushort*)alloc((size_t)NN * 256 * 2);
    ushort* h1b  = (ushort*)alloc((size_t)NN * 256 * 2);
    float* buf1  = (float*)alloc((size_t)NN * 256 * 4);
    float* buf2  = (float*)alloc((size_t)NN * 128 * 4);
    ushort* wtb  = (ushort*)alloc((size_t)3 * 768 * 256 * 2);
    int* adj     = (int*)alloc((size_t)NE * 4);
    int* off     = (int*)alloc((size_t)(NN + 1) * 4);
    int* deg     = (int*)alloc((size_t)NN * 4);
    int* cursor  = (int*)alloc((size_t)NN * 4);
    int* cntrel  = (int*)alloc((size_t)2 * NN * 4);
    int* csum    = (int*)alloc(128 * 4);
    float* inv   = (float*)alloc((size_t)2 * NN * 4);
    float* part  = (float*)alloc((size_t)BNG * 512 * 4);
    float* ss    = (float*)alloc(512 * 4);
    int* goff    = (int*)alloc(65 * 4);

    dim3 blk(256);
    const int EB = NE / 256;
    const int SCB = (NN + 255) / 256;
    const int nMT = (NN + 127) / 128;  // 157 row tiles

    auto build_csr = [&](const int* ei, const int* et) {
        hipMemsetAsync(deg, 0, NN * 4, stream);
        hipMemsetAsync(cursor, 0, NN * 4, stream);
        hipMemsetAsync(cntrel, 0, 2 * NN * 4, stream);
        k_count_edges<<<EB, blk, 0, stream>>>(ei, et, deg, cntrel);
        k_scan_local<<<SCB, blk, 0, stream>>>(deg, off, csum, NN);
        k_scan_csum<<<1, 128, 0, stream>>>(csum, off + NN, SCB);
        k_scan_add<<<SCB, blk, 0, stream>>>(off, csum, NN);
        k_fill<<<EB, blk, 0, stream>>>(ei, et, off, cursor, adj);
        k_invcnt<<<(2 * NN + 255) / 256, blk, 0, stream>>>(cntrel, inv);
    };

    auto run_layer = [&](const ushort* Abf, int K, const float* wroot, const float* wrel, const float* bias,
                         int C, float* buf, const float* g, const float* be,
                         bool bf16out, float* outf, ushort* outb) {
        k_cast_wtT<<<dim3(K / 32, C / 32, 3), blk, 0, stream>>>(wroot, wrel, wtb, K, C);
        int nblk = (C / 128) * nMT * 3;
        k_gemm_mfma<<<nblk, blk, 0, stream>>>(Abf, K, NN, wtb, bias, buf, h0b, h1b, C);
        if (C == 256)
            k_aggregate<256><<<(NN + 3) / 4, blk, 0, stream>>>(off, adj, inv, h0b, h1b, buf);
        else
            k_aggregate<128><<<(NN + 3) / 4, blk, 0, stream>>>(off, adj, inv, h0b, h1b, buf);
        k_bnstats<<<BNG, blk, 0, stream>>>(buf, part, C, NN);
        k_bnreduce<<<(C + 3) / 4, blk, 0, stream>>>(part, g, be, ss, C, 1.0f / NN);
        int nap = (NN * C / 4 + 255) / 256;
        if (bf16out)
            k_bnapply<true><<<nap, blk, 0, stream>>>(buf, ss, C, NN, nullptr, outb);
        else
            k_bnapply<false><<<nap, blk, 0, stream>>>(buf, ss, C, NN, outf, nullptr);
    };

    // ================= branch t =================
    build_csr(ei_t, et_t);
    k_cast_x<<<(NN * 768 / 4 + 255) / 256, blk, 0, stream>>>(x_t, xbig, NN * 768 / 4);
    run_layer(xbig, 768, w_t1_root, w_t1_rel, b_t1, 256, buf1, g_t1, be_t1, true, nullptr, xbig);
    run_layer(xbig, 256, w_t2_root, w_t2_rel, b_t2, 128, buf2, g_t2, be_t2, false, buf2, nullptr);
    k_goff_bs<<<1, 128, 0, stream>>>(bat_t, goff);
    k_pool<<<64, 512, 0, stream>>>(buf2, goff, (float*)d_out);

    // ================= branch p =================
    build_csr(ei_p, et_p);
    k_cast_x<<<(NN * 128 / 4 + 255) / 256, blk, 0, stream>>>(x_p, xbig, NN * 128 / 4);
    run_layer(xbig, 128, w_p1_root, w_p1_rel, b_p1, 256, buf1, g_p1, be_p1, true, nullptr, xbig);
    run_layer(xbig, 256, w_p2_root, w_p2_rel, b_p2, 128, buf2, g_p2, be_p2, false, buf2, nullptr);
    k_goff_bs<<<1, 128, 0, stream>>>(bat_p, goff);
    k_pool<<<64, 512, 0, stream>>>(buf2, goff, (float*)d_out + 64 * 128);
}

// Round 6
// 458.639 us; speedup vs baseline: 3.0338x; 1.2456x over previous
//
#include <hip/hip_runtime.h>

#define NN 20000
#define NE 320000
#define NB 64
#define BNG 128  // bnstats partial-sum blocks

typedef __attribute__((ext_vector_type(4))) float f32x4;
typedef __attribute__((ext_vector_type(8))) __bf16 bf16x8;

static __device__ __forceinline__ ushort f2bf(float f) {
    uint u = __builtin_bit_cast(uint, f);
    uint r = (u + 0x7fffu + ((u >> 16) & 1u)) >> 16;
    return (ushort)r;
}
static __device__ __forceinline__ float bf2f(ushort u) {
    return __builtin_bit_cast(float, (uint)u << 16);
}

#define GLD_LDS16(g, l)                                                                     \
    __builtin_amdgcn_global_load_lds((__attribute__((address_space(1))) void*)(g),          \
                                     (__attribute__((address_space(3))) void*)(l), 16, 0, 0)

// ---------------- CSR build (both branches in one pass; adj globally indexed) ----------------

__global__ __launch_bounds__(256) void k_count2(const int* __restrict__ ei_t, const int* __restrict__ et_t,
                                                const int* __restrict__ ei_p, const int* __restrict__ et_p,
                                                int* __restrict__ deg, int* __restrict__ cntrel) {
    int e = blockIdx.x * 256 + threadIdx.x;
    if (e >= 2 * NE) return;
    int br = e >= NE;
    int el = e - br * NE;
    const int* ei = br ? ei_p : ei_t;
    const int* et = br ? et_p : et_t;
    int dst = ei[NE + el];
    atomicAdd(&deg[br * NN + dst], 1);
    atomicAdd(&cntrel[br * 2 * NN + et[el] * NN + dst], 1);
}

__global__ __launch_bounds__(256) void k_scan_local(const int* __restrict__ deg, int* __restrict__ off,
                                                    int* __restrict__ csum, int n) {
    __shared__ int sh[256];
    int base = blockIdx.x * 256, tid = threadIdx.x;
    int v = (base + tid < n) ? deg[base + tid] : 0;
    sh[tid] = v; __syncthreads();
    for (int o = 1; o < 256; o <<= 1) {
        int t = (tid >= o) ? sh[tid - o] : 0;
        __syncthreads();
        sh[tid] += t;
        __syncthreads();
    }
    if (base + tid < n) off[base + tid] = sh[tid] - v;  // exclusive
    if (tid == 255) csum[blockIdx.x] = sh[255];
}

__global__ void k_scan_csum(int* __restrict__ csum, int* __restrict__ offN, int nc) {
    __shared__ int sh[256];
    int tid = threadIdx.x;
    int v = (tid < nc) ? csum[tid] : 0;
    sh[tid] = v; __syncthreads();
    for (int o = 1; o < 256; o <<= 1) {
        int t = (tid >= o) ? sh[tid - o] : 0;
        __syncthreads();
        sh[tid] += t;
        __syncthreads();
    }
    if (tid < nc) csum[tid] = sh[tid] - v;  // exclusive
    if (tid == 255) offN[0] = sh[255];      // grand total = 2*NE -> off[2*NN]
}

__global__ __launch_bounds__(256) void k_scan_add(int* __restrict__ off, const int* __restrict__ csum, int n) {
    int i = blockIdx.x * 256 + threadIdx.x;
    if (i < n) off[i] += csum[blockIdx.x];
}

__global__ __launch_bounds__(256) void k_fill2(const int* __restrict__ ei_t, const int* __restrict__ et_t,
                                               const int* __restrict__ ei_p, const int* __restrict__ et_p,
                                               const int* __restrict__ off, int* __restrict__ cursor,
                                               int* __restrict__ adj) {
    int e = blockIdx.x * 256 + threadIdx.x;
    if (e >= 2 * NE) return;
    int br = e >= NE;
    int el = e - br * NE;
    const int* ei = br ? ei_p : ei_t;
    const int* et = br ? et_p : et_t;
    int src = ei[el], dst = ei[NE + el], r = et[el];
    int g = br * NN + dst;
    int pos = atomicAdd(&cursor[g], 1);
    adj[off[g] + pos] = src | (r << 28);
}

__global__ void k_invcnt(const int* __restrict__ cntrel, float* __restrict__ inv) {
    int i = blockIdx.x * 256 + threadIdx.x;
    if (i >= 4 * NN) return;
    int c = cntrel[i];
    inv[i] = 1.0f / (float)(c > 0 ? c : 1);
}

// ---------------- casts ----------------

__global__ __launch_bounds__(256) void k_cast_x2(const float* __restrict__ xt, const float* __restrict__ xp,
                                                 ushort* __restrict__ ot, ushort* __restrict__ op,
                                                 int n4t, int n4p) {
    int i = blockIdx.x * 256 + threadIdx.x;
    const float* in; ushort* out; int j;
    if (i < n4t) { in = xt; out = ot; j = i; }
    else { j = i - n4t; if (j >= n4p) return; in = xp; out = op; }
    float4 v = *(const float4*)&in[(size_t)j * 4];
    ushort4 o;
    o.x = f2bf(v.x); o.y = f2bf(v.y); o.z = f2bf(v.z); o.w = f2bf(v.w);
    *(ushort4*)&out[(size_t)j * 4] = o;
}

// W [K][C] (root/rel0/rel1) -> Wt [3][C][K] bf16; all 4 layers in one dispatch
struct WtJob { const float* root; const float* rel; ushort* dst; int K; int C; };

__global__ __launch_bounds__(256) void k_cast_wt_all(WtJob j0, WtJob j1, WtJob j2, WtJob j3,
                                                     int c1, int c2, int c3) {
    __shared__ float tile[32][33];
    int bid = blockIdx.x;
    WtJob j; int lt;
    if (bid < c1) { j = j0; lt = bid; }
    else if (bid < c2) { j = j1; lt = bid - c1; }
    else if (bid < c3) { j = j2; lt = bid - c2; }
    else { j = j3; lt = bid - c3; }
    int nx = j.K >> 5, ny = j.C >> 5;
    int mat = lt / (nx * ny);
    int r2 = lt - mat * (nx * ny);
    int kx = r2 % nx, cy = r2 / nx;
    int KC = j.K * j.C;
    const float* W = (mat == 0) ? j.root : j.rel + (size_t)(mat - 1) * KC;
    int k0 = kx * 32, c0 = cy * 32;
    int tx = threadIdx.x & 31, ty = threadIdx.x >> 5;  // 32 x 8
#pragma unroll
    for (int i = 0; i < 4; i++)
        tile[ty + i * 8][tx] = W[(size_t)(k0 + ty + i * 8) * j.C + c0 + tx];
    __syncthreads();
#pragma unroll
    for (int i = 0; i < 4; i++)
        j.dst[(size_t)mat * KC + (size_t)(c0 + ty + i * 8) * j.K + k0 + tx] = f2bf(tile[tx][ty + i * 8]);
}

// ---------------- MFMA GEMM: per branch-job 3 products (root->fp32+bias, rel0/rel1->bf16) ----
// A [M,K] bf16 row-major; Wt [3][C][K] bf16. 128x128 tile, 4 waves, XCD-chunk swizzled 1-D grid.
// NBR=2 merges two same-shape jobs (layer 2 of both branches) into one dispatch.

struct GemmJob { const ushort* A; const ushort* Wt; const float* bias;
                 float* Droot; ushort* h0; ushort* h1; };

__global__ __launch_bounds__(256, 4) void k_gemm_mfma(GemmJob j0, GemmJob j1, int K, int M, int C, int NBR) {
    __shared__ ushort smem[2 * 128 * 64];
    ushort* As = smem;
    ushort* Bs = smem + 128 * 64;

    int nx = C >> 7;
    int perY = nx * 3 * NBR;
    int nwg = gridDim.x;
    int orig = blockIdx.x;
    int q = nwg >> 3, r = nwg & 7;
    int xcd = orig & 7, pos = orig >> 3;
    int wgid = (xcd < r) ? (xcd * (q + 1) + pos) : (r * (q + 1) + (xcd - r) * q + pos);
    int y = wgid / perY, rem = wgid - y * perY;
    int x = rem / (3 * NBR), zz = rem - x * (3 * NBR);
    int br = zz / 3, z = zz - br * 3;
    GemmJob j = br ? j1 : j0;

    const ushort* B = j.Wt + (size_t)z * C * K;
    int tid = threadIdx.x;
    int lane = tid & 63, wave = tid >> 6;
    int wr = wave >> 1, wc = wave & 1;
    int rowTile = y * 128, colTile = x * 128;

    f32x4 acc[4][4] = {};

    for (int k0 = 0; k0 < K; k0 += 64) {
        __syncthreads();
#pragma unroll
        for (int i = 0; i < 4; i++) {
            int id = i * 256 + tid;
            int rr = id >> 3, ck = id & 7;
            int garow = rowTile + rr;
            if (garow >= M) garow = M - 1;
            GLD_LDS16(j.A + (size_t)garow * K + k0 + ck * 8, &As[id * 8]);
            GLD_LDS16(B + (size_t)(colTile + rr) * K + k0 + ck * 8, &Bs[id * 8]);
        }
        __syncthreads();
#pragma unroll
        for (int kk = 0; kk < 2; kk++) {
            int kb = kk * 32 + (lane >> 4) * 8;
            bf16x8 af[4], bfr[4];
#pragma unroll
            for (int mi = 0; mi < 4; mi++)
                af[mi] = *(const bf16x8*)&As[(wr * 64 + mi * 16 + (lane & 15)) * 64 + kb];
#pragma unroll
            for (int ni = 0; ni < 4; ni++)
                bfr[ni] = *(const bf16x8*)&Bs[(wc * 64 + ni * 16 + (lane & 15)) * 64 + kb];
#pragma unroll
            for (int mi = 0; mi < 4; mi++)
#pragma unroll
                for (int ni = 0; ni < 4; ni++)
                    acc[mi][ni] = __builtin_amdgcn_mfma_f32_16x16x32_bf16(af[mi], bfr[ni], acc[mi][ni], 0, 0, 0);
        }
    }

    int lc = lane & 15, lr4 = (lane >> 4) * 4;
    if (z == 0) {
        // fp32 + bias, direct stores (full-line quarters, no amplification)
#pragma unroll
        for (int ni = 0; ni < 4; ni++) {
            int col = colTile + wc * 64 + ni * 16 + lc;
            float bj = j.bias[col];
#pragma unroll
            for (int mi = 0; mi < 4; mi++) {
#pragma unroll
                for (int jj = 0; jj < 4; jj++) {
                    int row = rowTile + wr * 64 + mi * 16 + lr4 + jj;
                    if (row < M) j.Droot[(size_t)row * C + col] = acc[mi][ni][jj] + bj;
                }
            }
        }
    } else {
        // bf16 h output: bounce through LDS (swizzled) -> coalesced 16B stores
        ushort* H = (z == 1) ? j.h0 : j.h1;
        __syncthreads();  // all LDS reads of K-loop done before overwrite
        ushort* Ep = smem;  // [128][128] ushorts = 32 KB
#pragma unroll
        for (int ni = 0; ni < 4; ni++) {
            int col = wc * 64 + ni * 16 + lc;
#pragma unroll
            for (int mi = 0; mi < 4; mi++) {
#pragma unroll
                for (int jj = 0; jj < 4; jj++) {
                    int rloc = wr * 64 + mi * 16 + lr4 + jj;
                    int chunk = (col >> 3) ^ (rloc & 7);   // 4-bit chunk, low-3-bit XOR (bijective/row)
                    Ep[rloc * 128 + (chunk << 3) + (col & 7)] = f2bf(acc[mi][ni][jj]);
                }
            }
        }
        __syncthreads();
        // 128 rows x 16 chunks of 16B = 2048 chunks (R5 bug: covered only 1024)
#pragma unroll
        for (int it = 0; it < 8; it++) {
            int cid = it * 256 + tid;
            int rloc = cid >> 4, cc = cid & 15;
            int grow = rowTile + rloc;
            if (grow < M) {
                int4 v = *(const int4*)&Ep[rloc * 128 + ((cc ^ (rloc & 7)) << 3)];
                *(int4*)&H[(size_t)grow * C + colTile + cc * 8] = v;
            }
        }
    }
}

// ---------------- aggregation: out += sum_r mean_r(h) ----------------
// C=256: 2 nodes/block, 2 waves/node (edge-range split) x 2-unroll = 4 chains/node.

__global__ __launch_bounds__(256) void k_agg256(const int* __restrict__ off, const int* __restrict__ adj,
                                                const float* __restrict__ inv, const ushort* __restrict__ h0,
                                                const ushort* __restrict__ h1, float* __restrict__ out) {
    __shared__ float4 sh[2][64];
    int wave = threadIdx.x >> 6, lane = threadIdx.x & 63;
    int nb = wave >> 1, w = wave & 1;
    int node = blockIdx.x * 2 + nb;
    int s = off[node], e = off[node + 1];
    float w0 = inv[node], w1 = inv[NN + node];
    int len = e - s;
    int mid = s + ((len + 1) >> 1);
    int i0 = w ? mid : s;
    int i1 = w ? e : mid;
    float4 a0 = make_float4(0.f, 0.f, 0.f, 0.f);
    float4 a1 = make_float4(0.f, 0.f, 0.f, 0.f);
    int i = i0;
    for (; i + 1 < i1; i += 2) {
        int v0 = adj[i], v1 = adj[i + 1];
        int s0 = v0 & 0x0FFFFFFF, r0 = v0 >> 28;
        int s1 = v1 & 0x0FFFFFFF, r1 = v1 >> 28;
        const ushort* hp0 = r0 ? h1 : h0; float wt0 = r0 ? w1 : w0;
        const ushort* hp1 = r1 ? h1 : h0; float wt1 = r1 ? w1 : w0;
        ushort4 x0 = *(const ushort4*)&hp0[(size_t)s0 * 256 + lane * 4];
        ushort4 x1 = *(const ushort4*)&hp1[(size_t)s1 * 256 + lane * 4];
        a0.x += wt0 * bf2f(x0.x); a0.y += wt0 * bf2f(x0.y);
        a0.z += wt0 * bf2f(x0.z); a0.w += wt0 * bf2f(x0.w);
        a1.x += wt1 * bf2f(x1.x); a1.y += wt1 * bf2f(x1.y);
        a1.z += wt1 * bf2f(x1.z); a1.w += wt1 * bf2f(x1.w);
    }
    if (i < i1) {
        int v0 = adj[i];
        int s0 = v0 & 0x0FFFFFFF, r0 = v0 >> 28;
        const ushort* hp0 = r0 ? h1 : h0; float wt0 = r0 ? w1 : w0;
        ushort4 x0 = *(const ushort4*)&hp0[(size_t)s0 * 256 + lane * 4];
        a0.x += wt0 * bf2f(x0.x); a0.y += wt0 * bf2f(x0.y);
        a0.z += wt0 * bf2f(x0.z); a0.w += wt0 * bf2f(x0.w);
    }
    float4 a = make_float4(a0.x + a1.x, a0.y + a1.y, a0.z + a1.z, a0.w + a1.w);
    if (w) sh[nb][lane] = a;
    __syncthreads();
    if (!w) {
        float4 b = sh[nb][lane];
        float* p = &out[(size_t)node * 256 + lane * 4];
        float4 o = *(float4*)p;
        o.x += a.x + b.x; o.y += a.y + b.y; o.z += a.z + b.z; o.w += a.w + b.w;
        *(float4*)p = o;
    }
}

// C=128 merged (both branches): 4 nodes/block, lane-parity edge split x 2-unroll.
__global__ __launch_bounds__(256) void k_agg128(const int* __restrict__ offAll, const int* __restrict__ adj,
                                                const float* __restrict__ invAll,
                                                const ushort* __restrict__ h0t, const ushort* __restrict__ h1t,
                                                float* __restrict__ outt,
                                                const ushort* __restrict__ h0p, const ushort* __restrict__ h1p,
                                                float* __restrict__ outp) {
    int half = gridDim.x >> 1;
    int br = blockIdx.x >= half;
    int bb = blockIdx.x - br * half;
    int wave = threadIdx.x >> 6, lane = threadIdx.x & 63;
    int node = bb * 4 + wave;
    const int* off = offAll + br * NN;
    const float* inv = invAll + (size_t)br * 2 * NN;
    const ushort* h0 = br ? h0p : h0t;
    const ushort* h1 = br ? h1p : h1t;
    float* out = br ? outp : outt;
    int s = off[node], e = off[node + 1];
    float w0 = inv[node], w1 = inv[NN + node];
    int l32 = lane & 31, ep = lane >> 5;
    float4 a0 = make_float4(0.f, 0.f, 0.f, 0.f);
    float4 a1 = make_float4(0.f, 0.f, 0.f, 0.f);
    int i = s + ep;
    for (; i + 2 < e; i += 4) {
        int v0 = adj[i], v1 = adj[i + 2];
        int s0 = v0 & 0x0FFFFFFF, r0 = v0 >> 28;
        int s1 = v1 & 0x0FFFFFFF, r1 = v1 >> 28;
        const ushort* hp0 = r0 ? h1 : h0; float wt0 = r0 ? w1 : w0;
        const ushort* hp1 = r1 ? h1 : h0; float wt1 = r1 ? w1 : w0;
        ushort4 x0 = *(const ushort4*)&hp0[(size_t)s0 * 128 + l32 * 4];
        ushort4 x1 = *(const ushort4*)&hp1[(size_t)s1 * 128 + l32 * 4];
        a0.x += wt0 * bf2f(x0.x); a0.y += wt0 * bf2f(x0.y);
        a0.z += wt0 * bf2f(x0.z); a0.w += wt0 * bf2f(x0.w);
        a1.x += wt1 * bf2f(x1.x); a1.y += wt1 * bf2f(x1.y);
        a1.z += wt1 * bf2f(x1.z); a1.w += wt1 * bf2f(x1.w);
    }
    if (i < e) {
        int v0 = adj[i];
        int s0 = v0 & 0x0FFFFFFF, r0 = v0 >> 28;
        const ushort* hp0 = r0 ? h1 : h0; float wt0 = r0 ? w1 : w0;
        ushort4 x0 = *(const ushort4*)&hp0[(size_t)s0 * 128 + l32 * 4];
        a0.x += wt0 * bf2f(x0.x); a0.y += wt0 * bf2f(x0.y);
        a0.z += wt0 * bf2f(x0.z); a0.w += wt0 * bf2f(x0.w);
    }
    float ax = a0.x + a1.x, ay = a0.y + a1.y, az = a0.z + a1.z, aw = a0.w + a1.w;
    ax += __shfl_xor(ax, 32); ay += __shfl_xor(ay, 32);
    az += __shfl_xor(az, 32); aw += __shfl_xor(aw, 32);
    if (ep == 0) {
        float* p = &out[(size_t)node * 128 + l32 * 4];
        float4 o = *(float4*)p;
        o.x += ax; o.y += ay; o.z += az; o.w += aw;
        *(float4*)p = o;
    }
}

// ---------------- batchnorm + leaky (atomic-free two-stage stats; optional 2-branch grid.y) ----

__global__ __launch_bounds__(256) void k_bnstats(const float* __restrict__ x0, const float* __restrict__ x1,
                                                 float* __restrict__ part, int C, int M) {
    int br = blockIdx.y;
    const float* x = br ? x1 : x0;
    float* P = part + (size_t)br * 2 * C * BNG;
    int tid = threadIdx.x;
    int groups = 256 / C;
    int col = tid & (C - 1);
    int rg = tid / C;
    float s = 0.f, s2 = 0.f;
    for (int row = blockIdx.x * groups + rg; row < M; row += BNG * groups) {
        float v = x[(size_t)row * C + col];
        s += v; s2 += v * v;
    }
    __shared__ float shs[256], shq[256];
    shs[tid] = s; shq[tid] = s2;
    __syncthreads();
    if (tid < C) {
        for (int g = 1; g < groups; g++) { shs[tid] += shs[tid + g * C]; shq[tid] += shq[tid + g * C]; }
        P[(size_t)tid * BNG + blockIdx.x] = shs[tid];
        P[(size_t)(C + tid) * BNG + blockIdx.x] = shq[tid];
    }
}

__global__ __launch_bounds__(256) void k_bnreduce(const float* __restrict__ part,
                                                  const float* __restrict__ g0, const float* __restrict__ be0,
                                                  const float* __restrict__ g1, const float* __restrict__ be1,
                                                  float* __restrict__ ss, int C, float invM) {
    int br = blockIdx.y;
    const float* P = part + (size_t)br * 2 * C * BNG;
    const float* g = br ? g1 : g0;
    const float* be = br ? be1 : be0;
    float* S = ss + br * 2 * C;
    int wv = threadIdx.x >> 6, lane = threadIdx.x & 63;
    int c = blockIdx.x * 4 + wv;
    if (c >= C) return;
    float s = P[(size_t)c * BNG + lane] + P[(size_t)c * BNG + 64 + lane];
    float s2 = P[(size_t)(C + c) * BNG + lane] + P[(size_t)(C + c) * BNG + 64 + lane];
#pragma unroll
    for (int o = 32; o >= 1; o >>= 1) {
        s += __shfl_xor(s, o, 64);
        s2 += __shfl_xor(s2, o, 64);
    }
    if (lane == 0) {
        float mu = s * invM;
        float var = s2 * invM - mu * mu;
        float sc = g[c] * rsqrtf(var + 1e-5f);
        S[c] = sc;
        S[C + c] = be[c] - mu * sc;
    }
}

template <bool BF16OUT>
__global__ __launch_bounds__(256) void k_bnapply(const float* __restrict__ x0, const float* __restrict__ x1,
                                                 const float* __restrict__ ss, int C, int M,
                                                 float* __restrict__ of0, float* __restrict__ of1,
                                                 ushort* __restrict__ ob0, ushort* __restrict__ ob1) {
    int br = blockIdx.y;
    const float* x = br ? x1 : x0;
    const float* S = ss + br * 2 * C;
    int i = blockIdx.x * 256 + threadIdx.x;
    int total4 = M * C / 4;
    if (i >= total4) return;
    float4 v = *(const float4*)&x[(size_t)i * 4];
    int c0 = (i * 4) & (C - 1);
    float y0 = v.x * S[c0 + 0] + S[C + c0 + 0];
    float y1 = v.y * S[c0 + 1] + S[C + c0 + 1];
    float y2 = v.z * S[c0 + 2] + S[C + c0 + 2];
    float y3 = v.w * S[c0 + 3] + S[C + c0 + 3];
    y0 = y0 >= 0.f ? y0 : 0.01f * y0;
    y1 = y1 >= 0.f ? y1 : 0.01f * y1;
    y2 = y2 >= 0.f ? y2 : 0.01f * y2;
    y3 = y3 >= 0.f ? y3 : 0.01f * y3;
    if (BF16OUT) {
        ushort* ob = br ? ob1 : ob0;
        ushort4 o;
        o.x = f2bf(y0); o.y = f2bf(y1); o.z = f2bf(y2); o.w = f2bf(y3);
        *(ushort4*)&ob[(size_t)i * 4] = o;
    } else {
        float* of = br ? of1 : of0;
        float4 o = make_float4(y0, y1, y2, y3);
        *(float4*)&of[(size_t)i * 4] = o;
    }
}

// ---------------- pooling ----------------

__global__ void k_goff2(const int* __restrict__ bt, const int* __restrict__ bp, int* __restrict__ goff) {
    int tid = threadIdx.x;
    const int* b; int idx, slot;
    if (tid < 65) { b = bt; idx = tid; slot = tid; }
    else if (tid >= 128 && tid < 193) { b = bp; idx = tid - 128; slot = 65 + (tid - 128); }
    else return;
    int lo = 0, hi = NN;
    while (lo < hi) {
        int mid = (lo + hi) >> 1;
        if (b[mid] < idx) lo = mid + 1; else hi = mid;
    }
    goff[slot] = lo;
}

__global__ __launch_bounds__(512) void k_pool2(const float* __restrict__ xt, const float* __restrict__ xp,
                                               const int* __restrict__ goff, float* __restrict__ out) {
    int blk = blockIdx.x;
    int br = blk >> 6, b = blk & 63;
    const float* x = br ? xp : xt;
    const int* go = goff + br * 65;
    int t = threadIdx.x & 127, rg = threadIdx.x >> 7;
    __shared__ float sh[512];
    int s = go[b], e = go[b + 1];
    float acc = 0.f;
    for (int r = s + rg; r < e; r += 4) acc += x[(size_t)r * 128 + t];
    sh[threadIdx.x] = acc;
    __syncthreads();
    if (rg == 0) {
        float v = sh[t] + sh[128 + t] + sh[256 + t] + sh[384 + t];
        int cnt = e - s;
        out[(br * 64 + b) * 128 + t] = v / (float)(cnt > 0 ? cnt : 1);
    }
}

// ---------------- host orchestration ----------------

extern "C" void kernel_launch(void* const* d_in, const int* in_sizes, int n_in,
                              void* d_out, int out_size, void* d_ws, size_t ws_size,
                              hipStream_t stream) {
    const float* x_t = (const float*)d_in[0];
    const float* x_p = (const float*)d_in[1];
    const int* ei_t = (const int*)d_in[2];
    const int* et_t = (const int*)d_in[3];
    const int* bat_t = (const int*)d_in[4];
    const int* ei_p = (const int*)d_in[5];
    const int* et_p = (const int*)d_in[6];
    const int* bat_p = (const int*)d_in[7];
    const float* w_t1_rel = (const float*)d_in[8];
    const float* w_t1_root = (const float*)d_in[9];
    const float* b_t1 = (const float*)d_in[10];
    const float* w_t2_rel = (const float*)d_in[11];
    const float* w_t2_root = (const float*)d_in[12];
    const float* b_t2 = (const float*)d_in[13];
    const float* w_p1_rel = (const float*)d_in[14];
    const float* w_p1_root = (const float*)d_in[15];
    const float* b_p1 = (const float*)d_in[16];
    const float* w_p2_rel = (const float*)d_in[17];
    const float* w_p2_root = (const float*)d_in[18];
    const float* b_p2 = (const float*)d_in[19];
    const float* g_t1 = (const float*)d_in[20]; const float* be_t1 = (const float*)d_in[21];
    const float* g_t2 = (const float*)d_in[22]; const float* be_t2 = (const float*)d_in[23];
    const float* g_p1 = (const float*)d_in[24]; const float* be_p1 = (const float*)d_in[25];
    const float* g_p2 = (const float*)d_in[26]; const float* be_p2 = (const float*)d_in[27];

    char* wp = (char*)d_ws;
    auto alloc = [&](size_t b) -> void* {
        void* p = (void*)wp;
        wp += (b + 255) & ~(size_t)255;
        return p;
    };
    ushort* xt_bf = (ushort*)alloc((size_t)NN * 768 * 2);  // 30.72 MB; later: buf2t | buf2p | a1p
    ushort* xp_bf = (ushort*)alloc((size_t)NN * 128 * 2);
    ushort* h0b   = (ushort*)alloc((size_t)NN * 256 * 2);  // layer2: [h0t | h0p] halves
    ushort* h1b   = (ushort*)alloc((size_t)NN * 256 * 2);
    float* buf1   = (float*)alloc((size_t)NN * 256 * 4);   // shared sequentially t1 then p1
    ushort* a1t   = (ushort*)alloc((size_t)NN * 256 * 2);
    ushort* wtb   = (ushort*)alloc((size_t)(3 * 768 * 256 + 3 * 128 * 256 + 2 * 3 * 256 * 128) * 2);
    int* adj      = (int*)alloc((size_t)2 * NE * 4);
    int* off      = (int*)alloc((size_t)(2 * NN + 1) * 4);
    int* csrz     = (int*)alloc((size_t)8 * NN * 4);       // deg[2NN] | cursor[2NN] | cntrel[4NN]
    int* csum     = (int*)alloc(256 * 4);
    float* inv    = (float*)alloc((size_t)4 * NN * 4);
    float* part   = (float*)alloc((size_t)2 * 2 * 256 * BNG * 4);
    float* ss     = (float*)alloc(1024 * 4);
    int* goff     = (int*)alloc(130 * 4);

    // aliases inside dead xt_bf region (x_t bf16 consumed by t1 GEMM)
    float* buf2t = (float*)xt_bf;
    float* buf2p = buf2t + (size_t)NN * 128;
    ushort* a1p  = (ushort*)(buf2p + (size_t)NN * 128);

    int* deg = csrz;
    int* cursor = csrz + 2 * NN;
    int* cntrel = csrz + 4 * NN;

    ushort* wt_t1 = wtb;
    ushort* wt_p1 = wt_t1 + 3 * 768 * 256;
    ushort* wt_t2 = wt_p1 + 3 * 128 * 256;
    ushort* wt_p2 = wt_t2 + 3 * 256 * 128;

    dim3 blk(256);
    const int EB2 = (2 * NE) / 256;          // 2500
    const int SCB2 = (2 * NN + 255) / 256;   // 157
    const int nMT = (NN + 127) / 128;        // 157 row panels

    // ---- prep: CSR both branches, casts ----
    hipMemsetAsync(csrz, 0, (size_t)8 * NN * 4, stream);
    k_count2<<<EB2, blk, 0, stream>>>(ei_t, et_t, ei_p, et_p, deg, cntrel);
    k_scan_local<<<SCB2, blk, 0, stream>>>(deg, off, csum, 2 * NN);
    k_scan_csum<<<1, 256, 0, stream>>>(csum, off + 2 * NN, SCB2);
    k_scan_add<<<SCB2, blk, 0, stream>>>(off, csum, 2 * NN);
    k_fill2<<<EB2, blk, 0, stream>>>(ei_t, et_t, ei_p, et_p, off, cursor, adj);
    k_invcnt<<<(4 * NN + 255) / 256, blk, 0, stream>>>(cntrel, inv);

    int n4t = NN * 768 / 4, n4p = NN * 128 / 4;
    k_cast_x2<<<(n4t + n4p + 255) / 256, blk, 0, stream>>>(x_t, x_p, xt_bf, xp_bf, n4t, n4p);

    WtJob j0 = {w_t1_root, w_t1_rel, wt_t1, 768, 256};
    WtJob j1 = {w_p1_root, w_p1_rel, wt_p1, 128, 256};
    WtJob j2 = {w_t2_root, w_t2_rel, wt_t2, 256, 128};
    WtJob j3 = {w_p2_root, w_p2_rel, wt_p2, 256, 128};
    k_cast_wt_all<<<864, blk, 0, stream>>>(j0, j1, j2, j3, 576, 672, 768);

    GemmJob G;

    // ---- t layer 1: [20000,768] -> 256 ----
    G = {xt_bf, wt_t1, b_t1, buf1, h0b, h1b};
    k_gemm_mfma<<<2 * nMT * 3, blk, 0, stream>>>(G, G, 768, NN, 256, 1);
    k_agg256<<<NN / 2, blk, 0, stream>>>(off, adj, inv, h0b, h1b, buf1);
    k_bnstats<<<dim3(BNG, 1), blk, 0, stream>>>(buf1, buf1, part, 256, NN);
    k_bnreduce<<<dim3(64, 1), blk, 0, stream>>>(part, g_t1, be_t1, g_t1, be_t1, ss, 256, 1.0f / NN);
    k_bnapply<true><<<dim3((NN * 256 / 4 + 255) / 256, 1), blk, 0, stream>>>(
        buf1, buf1, ss, 256, NN, nullptr, nullptr, a1t, a1t);

    // ---- p layer 1: [20000,128] -> 256 ----
    G = {xp_bf, wt_p1, b_p1, buf1, h0b, h1b};
    k_gemm_mfma<<<2 * nMT * 3, blk, 0, stream>>>(G, G, 128, NN, 256, 1);
    k_agg256<<<NN / 2, blk, 0, stream>>>(off + NN, adj, inv + 2 * NN, h0b, h1b, buf1);
    k_bnstats<<<dim3(BNG, 1), blk, 0, stream>>>(buf1, buf1, part, 256, NN);
    k_bnreduce<<<dim3(64, 1), blk, 0, stream>>>(part, g_p1, be_p1, g_p1, be_p1, ss, 256, 1.0f / NN);
    k_bnapply<true><<<dim3((NN * 256 / 4 + 255) / 256, 1), blk, 0, stream>>>(
        buf1, buf1, ss, 256, NN, nullptr, nullptr, a1p, a1p);

    // ---- layer 2, both branches merged: [20000,256] -> 128 ----
    ushort* h0t = h0b;                       ushort* h0p = h0b + (size_t)NN * 128;
    ushort* h1t = h1b;                       ushort* h1p = h1b + (size_t)NN * 128;
    GemmJob Gt = {a1t, wt_t2, b_t2, buf2t, h0t, h1t};
    GemmJob Gp = {a1p, wt_p2, b_p2, buf2p, h0p, h1p};
    k_gemm_mfma<<<1 * nMT * 3 * 2, blk, 0, stream>>>(Gt, Gp, 256, NN, 128, 2);
    k_agg128<<<2 * (NN / 4), blk, 0, stream>>>(off, adj, inv, h0t, h1t, buf2t, h0p, h1p, buf2p);
    k_bnstats<<<dim3(BNG, 2), blk, 0, stream>>>(buf2t, buf2p, part, 128, NN);
    k_bnreduce<<<dim3(32, 2), blk, 0, stream>>>(part, g_t2, be_t2, g_p2, be_p2, ss, 128, 1.0f / NN);
    k_bnapply<false><<<dim3((NN * 128 / 4 + 255) / 256, 2), blk, 0, stream>>>(
        buf2t, buf2p, ss, 128, NN, buf2t, buf2p, nullptr, nullptr);

    // ---- pool both ----
    k_goff2<<<1, 256, 0, stream>>>(bat_t, bat_p, goff);
    k_pool2<<<128, 512, 0, stream>>>(buf2t, buf2p, goff, (float*)d_out);
}

// Round 7
// 411.235 us; speedup vs baseline: 3.3835x; 1.1153x over previous
//
#include <hip/hip_runtime.h>

#define NN 20000
#define NE 320000
#define NB 64
#define BNG 128  // bnstats partial-sum blocks

typedef __attribute__((ext_vector_type(4))) float f32x4;
typedef __attribute__((ext_vector_type(8))) __bf16 bf16x8;

static __device__ __forceinline__ ushort f2bf(float f) {
    uint u = __builtin_bit_cast(uint, f);
    uint r = (u + 0x7fffu + ((u >> 16) & 1u)) >> 16;
    return (ushort)r;
}
static __device__ __forceinline__ float bf2f(ushort u) {
    return __builtin_bit_cast(float, (uint)u << 16);
}

#define GLD_LDS16(g, l)                                                                     \
    __builtin_amdgcn_global_load_lds((__attribute__((address_space(1))) void*)(g),          \
                                     (__attribute__((address_space(3))) void*)(l), 16, 0, 0)

// ---------------- CSR build: ONE atomic per edge ----------------
// pass 1: pos = atomicAdd(deg[g]); pass 2 (atomic-free): adj[off[g]+pos] = src|rel<<28

__global__ __launch_bounds__(256) void k_countpos(const int* __restrict__ ei_t, const int* __restrict__ ei_p,
                                                  int* __restrict__ deg, int* __restrict__ posArr) {
    int e = blockIdx.x * 256 + threadIdx.x;
    if (e >= 2 * NE) return;
    int br = e >= NE;
    int el = e - br * NE;
    const int* ei = br ? ei_p : ei_t;
    int dst = ei[NE + el];
    posArr[e] = atomicAdd(&deg[br * NN + dst], 1);
}

__global__ __launch_bounds__(256) void k_scan_local(const int* __restrict__ deg, int* __restrict__ off,
                                                    int* __restrict__ csum, int n) {
    __shared__ int sh[256];
    int base = blockIdx.x * 256, tid = threadIdx.x;
    int v = (base + tid < n) ? deg[base + tid] : 0;
    sh[tid] = v; __syncthreads();
    for (int o = 1; o < 256; o <<= 1) {
        int t = (tid >= o) ? sh[tid - o] : 0;
        __syncthreads();
        sh[tid] += t;
        __syncthreads();
    }
    if (base + tid < n) off[base + tid] = sh[tid] - v;  // exclusive
    if (tid == 255) csum[blockIdx.x] = sh[255];
}

__global__ void k_scan_csum(int* __restrict__ csum, int* __restrict__ offN, int nc) {
    __shared__ int sh[256];
    int tid = threadIdx.x;
    int v = (tid < nc) ? csum[tid] : 0;
    sh[tid] = v; __syncthreads();
    for (int o = 1; o < 256; o <<= 1) {
        int t = (tid >= o) ? sh[tid - o] : 0;
        __syncthreads();
        sh[tid] += t;
        __syncthreads();
    }
    if (tid < nc) csum[tid] = sh[tid] - v;  // exclusive
    if (tid == 255) offN[0] = sh[255];      // grand total = 2*NE -> off[2*NN]
}

__global__ __launch_bounds__(256) void k_scan_add(int* __restrict__ off, const int* __restrict__ csum, int n) {
    int i = blockIdx.x * 256 + threadIdx.x;
    if (i < n) off[i] += csum[blockIdx.x];
}

__global__ __launch_bounds__(256) void k_fillpos(const int* __restrict__ ei_t, const int* __restrict__ et_t,
                                                 const int* __restrict__ ei_p, const int* __restrict__ et_p,
                                                 const int* __restrict__ off, const int* __restrict__ posArr,
                                                 int* __restrict__ adj) {
    int e = blockIdx.x * 256 + threadIdx.x;
    if (e >= 2 * NE) return;
    int br = e >= NE;
    int el = e - br * NE;
    const int* ei = br ? ei_p : ei_t;
    const int* et = br ? et_p : et_t;
    int src = ei[el], dst = ei[NE + el], r = et[el];
    int g = br * NN + dst;
    adj[off[g] + posArr[e]] = src | (r << 28);
}

// ---------------- casts ----------------

__global__ __launch_bounds__(256) void k_cast_x2(const float* __restrict__ xt, const float* __restrict__ xp,
                                                 ushort* __restrict__ ot, ushort* __restrict__ op,
                                                 int n4t, int n4p) {
    int i = blockIdx.x * 256 + threadIdx.x;
    const float* in; ushort* out; int j;
    if (i < n4t) { in = xt; out = ot; j = i; }
    else { j = i - n4t; if (j >= n4p) return; in = xp; out = op; }
    float4 v = *(const float4*)&in[(size_t)j * 4];
    ushort4 o;
    o.x = f2bf(v.x); o.y = f2bf(v.y); o.z = f2bf(v.z); o.w = f2bf(v.w);
    *(ushort4*)&out[(size_t)j * 4] = o;
}

// W [K][C] (root/rel0/rel1) -> Wt [3][C][K] bf16; all 4 layers in one dispatch
struct WtJob { const float* root; const float* rel; ushort* dst; int K; int C; };

__global__ __launch_bounds__(256) void k_cast_wt_all(WtJob j0, WtJob j1, WtJob j2, WtJob j3,
                                                     int c1, int c2, int c3) {
    __shared__ float tile[32][33];
    int bid = blockIdx.x;
    WtJob j; int lt;
    if (bid < c1) { j = j0; lt = bid; }
    else if (bid < c2) { j = j1; lt = bid - c1; }
    else if (bid < c3) { j = j2; lt = bid - c2; }
    else { j = j3; lt = bid - c3; }
    int nx = j.K >> 5, ny = j.C >> 5;
    int mat = lt / (nx * ny);
    int r2 = lt - mat * (nx * ny);
    int kx = r2 % nx, cy = r2 / nx;
    int KC = j.K * j.C;
    const float* W = (mat == 0) ? j.root : j.rel + (size_t)(mat - 1) * KC;
    int k0 = kx * 32, c0 = cy * 32;
    int tx = threadIdx.x & 31, ty = threadIdx.x >> 5;  // 32 x 8
#pragma unroll
    for (int i = 0; i < 4; i++)
        tile[ty + i * 8][tx] = W[(size_t)(k0 + ty + i * 8) * j.C + c0 + tx];
    __syncthreads();
#pragma unroll
    for (int i = 0; i < 4; i++)
        j.dst[(size_t)mat * KC + (size_t)(c0 + ty + i * 8) * j.K + k0 + tx] = f2bf(tile[tx][ty + i * 8]);
}

// ---------------- MFMA GEMM: per branch-job 3 products (root->fp32+bias, rel0/rel1->bf16) ----
// A [M,K] bf16 row-major; Wt [3][C][K] bf16. 128x128 tile, 4 waves, XCD-chunk swizzled 1-D grid.
// NBR=2 merges two same-shape jobs (layer 2 of both branches) into one dispatch.

struct GemmJob { const ushort* A; const ushort* Wt; const float* bias;
                 float* Droot; ushort* h0; ushort* h1; };

__global__ __launch_bounds__(256, 4) void k_gemm_mfma(GemmJob j0, GemmJob j1, int K, int M, int C, int NBR) {
    __shared__ ushort smem[2 * 128 * 64];
    ushort* As = smem;
    ushort* Bs = smem + 128 * 64;

    int nx = C >> 7;
    int perY = nx * 3 * NBR;
    int nwg = gridDim.x;
    int orig = blockIdx.x;
    int q = nwg >> 3, r = nwg & 7;
    int xcd = orig & 7, pos = orig >> 3;
    int wgid = (xcd < r) ? (xcd * (q + 1) + pos) : (r * (q + 1) + (xcd - r) * q + pos);
    int y = wgid / perY, rem = wgid - y * perY;
    int x = rem / (3 * NBR), zz = rem - x * (3 * NBR);
    int br = zz / 3, z = zz - br * 3;
    GemmJob j = br ? j1 : j0;

    const ushort* B = j.Wt + (size_t)z * C * K;
    int tid = threadIdx.x;
    int lane = tid & 63, wave = tid >> 6;
    int wr = wave >> 1, wc = wave & 1;
    int rowTile = y * 128, colTile = x * 128;

    f32x4 acc[4][4] = {};

    for (int k0 = 0; k0 < K; k0 += 64) {
        __syncthreads();
#pragma unroll
        for (int i = 0; i < 4; i++) {
            int id = i * 256 + tid;
            int rr = id >> 3, ck = id & 7;
            int garow = rowTile + rr;
            if (garow >= M) garow = M - 1;
            GLD_LDS16(j.A + (size_t)garow * K + k0 + ck * 8, &As[id * 8]);
            GLD_LDS16(B + (size_t)(colTile + rr) * K + k0 + ck * 8, &Bs[id * 8]);
        }
        __syncthreads();
#pragma unroll
        for (int kk = 0; kk < 2; kk++) {
            int kb = kk * 32 + (lane >> 4) * 8;
            bf16x8 af[4], bfr[4];
#pragma unroll
            for (int mi = 0; mi < 4; mi++)
                af[mi] = *(const bf16x8*)&As[(wr * 64 + mi * 16 + (lane & 15)) * 64 + kb];
#pragma unroll
            for (int ni = 0; ni < 4; ni++)
                bfr[ni] = *(const bf16x8*)&Bs[(wc * 64 + ni * 16 + (lane & 15)) * 64 + kb];
#pragma unroll
            for (int mi = 0; mi < 4; mi++)
#pragma unroll
                for (int ni = 0; ni < 4; ni++)
                    acc[mi][ni] = __builtin_amdgcn_mfma_f32_16x16x32_bf16(af[mi], bfr[ni], acc[mi][ni], 0, 0, 0);
        }
    }

    int lc = lane & 15, lr4 = (lane >> 4) * 4;
    if (z == 0) {
        // fp32 + bias, direct stores
#pragma unroll
        for (int ni = 0; ni < 4; ni++) {
            int col = colTile + wc * 64 + ni * 16 + lc;
            float bj = j.bias[col];
#pragma unroll
            for (int mi = 0; mi < 4; mi++) {
#pragma unroll
                for (int jj = 0; jj < 4; jj++) {
                    int row = rowTile + wr * 64 + mi * 16 + lr4 + jj;
                    if (row < M) j.Droot[(size_t)row * C + col] = acc[mi][ni][jj] + bj;
                }
            }
        }
    } else {
        // bf16 h output: bounce through LDS (swizzled) -> coalesced 16B stores
        ushort* H = (z == 1) ? j.h0 : j.h1;
        __syncthreads();  // all LDS reads of K-loop done before overwrite
        ushort* Ep = smem;  // [128][128] ushorts = 32 KB
#pragma unroll
        for (int ni = 0; ni < 4; ni++) {
            int col = wc * 64 + ni * 16 + lc;
#pragma unroll
            for (int mi = 0; mi < 4; mi++) {
#pragma unroll
                for (int jj = 0; jj < 4; jj++) {
                    int rloc = wr * 64 + mi * 16 + lr4 + jj;
                    int chunk = (col >> 3) ^ (rloc & 7);   // 4-bit chunk, low-3-bit XOR (bijective/row)
                    Ep[rloc * 128 + (chunk << 3) + (col & 7)] = f2bf(acc[mi][ni][jj]);
                }
            }
        }
        __syncthreads();
        // 128 rows x 16 chunks of 16B = 2048 chunks
#pragma unroll
        for (int it = 0; it < 8; it++) {
            int cid = it * 256 + tid;
            int rloc = cid >> 4, cc = cid & 15;
            int grow = rowTile + rloc;
            if (grow < M) {
                int4 v = *(const int4*)&Ep[rloc * 128 + ((cc ^ (rloc & 7)) << 3)];
                *(int4*)&H[(size_t)grow * C + colTile + cc * 8] = v;
            }
        }
    }
}

// ---------------- aggregation: out += sum_r sum_{e in rel r}(h_r[src]) / max(cnt_r,1) ----------
// Per-rel accumulators + on-the-fly counts (rel branch is wave-uniform: all lanes share the edge).
// C=256: 2 nodes/block, 2 waves/node (edge-range split) x 2 chains.

__global__ __launch_bounds__(256) void k_agg256(const int* __restrict__ off, const int* __restrict__ adj,
                                                const ushort* __restrict__ h0, const ushort* __restrict__ h1,
                                                float* __restrict__ out) {
    __shared__ float4 shA[2][64];
    __shared__ float4 shB[2][64];
    __shared__ int shc[2][2];
    int wave = threadIdx.x >> 6, lane = threadIdx.x & 63;
    int nb = wave >> 1, w = wave & 1;
    int node = blockIdx.x * 2 + nb;
    int s = off[node], e = off[node + 1];
    int len = e - s;
    int mid = s + ((len + 1) >> 1);
    int i0 = w ? mid : s;
    int i1 = w ? e : mid;
    float4 a0 = make_float4(0.f, 0.f, 0.f, 0.f);  // rel0, chain A
    float4 a1 = make_float4(0.f, 0.f, 0.f, 0.f);  // rel1, chain A
    float4 b0 = make_float4(0.f, 0.f, 0.f, 0.f);  // rel0, chain B
    float4 b1 = make_float4(0.f, 0.f, 0.f, 0.f);  // rel1, chain B
    int c0 = 0, c1 = 0;
    int i = i0;
    for (; i + 1 < i1; i += 2) {
        int v0 = adj[i], v1 = adj[i + 1];
        int s0 = v0 & 0x0FFFFFFF, r0 = v0 >> 28;
        int s1 = v1 & 0x0FFFFFFF, r1 = v1 >> 28;
        const ushort* hp0 = r0 ? h1 : h0;
        const ushort* hp1 = r1 ? h1 : h0;
        ushort4 x0 = *(const ushort4*)&hp0[(size_t)s0 * 256 + lane * 4];
        ushort4 x1 = *(const ushort4*)&hp1[(size_t)s1 * 256 + lane * 4];
        if (r0) { a1.x += bf2f(x0.x); a1.y += bf2f(x0.y); a1.z += bf2f(x0.z); a1.w += bf2f(x0.w); c1++; }
        else    { a0.x += bf2f(x0.x); a0.y += bf2f(x0.y); a0.z += bf2f(x0.z); a0.w += bf2f(x0.w); c0++; }
        if (r1) { b1.x += bf2f(x1.x); b1.y += bf2f(x1.y); b1.z += bf2f(x1.z); b1.w += bf2f(x1.w); c1++; }
        else    { b0.x += bf2f(x1.x); b0.y += bf2f(x1.y); b0.z += bf2f(x1.z); b0.w += bf2f(x1.w); c0++; }
    }
    if (i < i1) {
        int v0 = adj[i];
        int s0 = v0 & 0x0FFFFFFF, r0 = v0 >> 28;
        const ushort* hp0 = r0 ? h1 : h0;
        ushort4 x0 = *(const ushort4*)&hp0[(size_t)s0 * 256 + lane * 4];
        if (r0) { a1.x += bf2f(x0.x); a1.y += bf2f(x0.y); a1.z += bf2f(x0.z); a1.w += bf2f(x0.w); c1++; }
        else    { a0.x += bf2f(x0.x); a0.y += bf2f(x0.y); a0.z += bf2f(x0.z); a0.w += bf2f(x0.w); c0++; }
    }
    float4 s0v = make_float4(a0.x + b0.x, a0.y + b0.y, a0.z + b0.z, a0.w + b0.w);
    float4 s1v = make_float4(a1.x + b1.x, a1.y + b1.y, a1.z + b1.z, a1.w + b1.w);
    if (w) {
        shA[nb][lane] = s0v; shB[nb][lane] = s1v;
        if (lane == 0) { shc[nb][0] = c0; shc[nb][1] = c1; }
    }
    __syncthreads();
    if (!w) {
        float4 t0 = shA[nb][lane], t1 = shB[nb][lane];
        c0 += shc[nb][0]; c1 += shc[nb][1];
        float w0 = 1.0f / (float)(c0 > 0 ? c0 : 1);
        float w1 = 1.0f / (float)(c1 > 0 ? c1 : 1);
        float* p = &out[(size_t)node * 256 + lane * 4];
        float4 o = *(float4*)p;
        o.x += (s0v.x + t0.x) * w0 + (s1v.x + t1.x) * w1;
        o.y += (s0v.y + t0.y) * w0 + (s1v.y + t1.y) * w1;
        o.z += (s0v.z + t0.z) * w0 + (s1v.z + t1.z) * w1;
        o.w += (s0v.w + t0.w) * w0 + (s1v.w + t1.w) * w1;
        *(float4*)p = o;
    }
}

// C=128 merged (both branches): 4 nodes/block (wave each), lane-parity edge split x 2 chains.
__global__ __launch_bounds__(256) void k_agg128(const int* __restrict__ offAll, const int* __restrict__ adj,
                                                const ushort* __restrict__ h0t, const ushort* __restrict__ h1t,
                                                float* __restrict__ outt,
                                                const ushort* __restrict__ h0p, const ushort* __restrict__ h1p,
                                                float* __restrict__ outp) {
    int half = gridDim.x >> 1;
    int br = blockIdx.x >= half;
    int bb = blockIdx.x - br * half;
    int wave = threadIdx.x >> 6, lane = threadIdx.x & 63;
    int node = bb * 4 + wave;
    const int* off = offAll + br * NN;
    const ushort* h0 = br ? h0p : h0t;
    const ushort* h1 = br ? h1p : h1t;
    float* out = br ? outp : outt;
    int s = off[node], e = off[node + 1];
    int l32 = lane & 31, ep = lane >> 5;
    float4 a0 = make_float4(0.f, 0.f, 0.f, 0.f);
    float4 a1 = make_float4(0.f, 0.f, 0.f, 0.f);
    float4 b0 = make_float4(0.f, 0.f, 0.f, 0.f);
    float4 b1 = make_float4(0.f, 0.f, 0.f, 0.f);
    int c0 = 0, c1 = 0;
    int i = s + ep;
    for (; i + 2 < e; i += 4) {
        int v0 = adj[i], v1 = adj[i + 2];
        int s0 = v0 & 0x0FFFFFFF, r0 = v0 >> 28;
        int s1 = v1 & 0x0FFFFFFF, r1 = v1 >> 28;
        const ushort* hp0 = r0 ? h1 : h0;
        const ushort* hp1 = r1 ? h1 : h0;
        ushort4 x0 = *(const ushort4*)&hp0[(size_t)s0 * 128 + l32 * 4];
        ushort4 x1 = *(const ushort4*)&hp1[(size_t)s1 * 128 + l32 * 4];
        if (r0) { a1.x += bf2f(x0.x); a1.y += bf2f(x0.y); a1.z += bf2f(x0.z); a1.w += bf2f(x0.w); c1++; }
        else    { a0.x += bf2f(x0.x); a0.y += bf2f(x0.y); a0.z += bf2f(x0.z); a0.w += bf2f(x0.w); c0++; }
        if (r1) { b1.x += bf2f(x1.x); b1.y += bf2f(x1.y); b1.z += bf2f(x1.z); b1.w += bf2f(x1.w); c1++; }
        else    { b0.x += bf2f(x1.x); b0.y += bf2f(x1.y); b0.z += bf2f(x1.z); b0.w += bf2f(x1.w); c0++; }
    }
    if (i < e) {
        int v0 = adj[i];
        int s0 = v0 & 0x0FFFFFFF, r0 = v0 >> 28;
        const ushort* hp0 = r0 ? h1 : h0;
        ushort4 x0 = *(const ushort4*)&hp0[(size_t)s0 * 128 + l32 * 4];
        if (r0) { a1.x += bf2f(x0.x); a1.y += bf2f(x0.y); a1.z += bf2f(x0.z); a1.w += bf2f(x0.w); c1++; }
        else    { a0.x += bf2f(x0.x); a0.y += bf2f(x0.y); a0.z += bf2f(x0.z); a0.w += bf2f(x0.w); c0++; }
    }
    float sx0 = a0.x + b0.x, sy0 = a0.y + b0.y, sz0 = a0.z + b0.z, sw0 = a0.w + b0.w;
    float sx1 = a1.x + b1.x, sy1 = a1.y + b1.y, sz1 = a1.z + b1.z, sw1 = a1.w + b1.w;
    sx0 += __shfl_xor(sx0, 32); sy0 += __shfl_xor(sy0, 32);
    sz0 += __shfl_xor(sz0, 32); sw0 += __shfl_xor(sw0, 32);
    sx1 += __shfl_xor(sx1, 32); sy1 += __shfl_xor(sy1, 32);
    sz1 += __shfl_xor(sz1, 32); sw1 += __shfl_xor(sw1, 32);
    c0 += __shfl_xor(c0, 32); c1 += __shfl_xor(c1, 32);
    if (ep == 0) {
        float w0 = 1.0f / (float)(c0 > 0 ? c0 : 1);
        float w1 = 1.0f / (float)(c1 > 0 ? c1 : 1);
        float* p = &out[(size_t)node * 128 + l32 * 4];
        float4 o = *(float4*)p;
        o.x += sx0 * w0 + sx1 * w1;
        o.y += sy0 * w0 + sy1 * w1;
        o.z += sz0 * w0 + sz1 * w1;
        o.w += sw0 * w0 + sw1 * w1;
        *(float4*)p = o;
    }
}

// ---------------- batchnorm + leaky (atomic-free two-stage stats; optional 2-branch grid.y) ----

__global__ __launch_bounds__(256) void k_bnstats(const float* __restrict__ x0, const float* __restrict__ x1,
                                                 float* __restrict__ part, int C, int M) {
    int br = blockIdx.y;
    const float* x = br ? x1 : x0;
    float* P = part + (size_t)br * 2 * C * BNG;
    int tid = threadIdx.x;
    int groups = 256 / C;
    int col = tid & (C - 1);
    int rg = tid / C;
    float s = 0.f, s2 = 0.f;
    for (int row = blockIdx.x * groups + rg; row < M; row += BNG * groups) {
        float v = x[(size_t)row * C + col];
        s += v; s2 += v * v;
    }
    __shared__ float shs[256], shq[256];
    shs[tid] = s; shq[tid] = s2;
    __syncthreads();
    if (tid < C) {
        for (int g = 1; g < groups; g++) { shs[tid] += shs[tid + g * C]; shq[tid] += shq[tid + g * C]; }
        P[(size_t)tid * BNG + blockIdx.x] = shs[tid];
        P[(size_t)(C + tid) * BNG + blockIdx.x] = shq[tid];
    }
}

__global__ __launch_bounds__(256) void k_bnreduce(const float* __restrict__ part,
                                                  const float* __restrict__ g0, const float* __restrict__ be0,
                                                  const float* __restrict__ g1, const float* __restrict__ be1,
                                                  float* __restrict__ ss, int C, float invM) {
    int br = blockIdx.y;
    const float* P = part + (size_t)br * 2 * C * BNG;
    const float* g = br ? g1 : g0;
    const float* be = br ? be1 : be0;
    float* S = ss + br * 2 * C;
    int wv = threadIdx.x >> 6, lane = threadIdx.x & 63;
    int c = blockIdx.x * 4 + wv;
    if (c >= C) return;
    float s = P[(size_t)c * BNG + lane] + P[(size_t)c * BNG + 64 + lane];
    float s2 = P[(size_t)(C + c) * BNG + lane] + P[(size_t)(C + c) * BNG + 64 + lane];
#pragma unroll
    for (int o = 32; o >= 1; o >>= 1) {
        s += __shfl_xor(s, o, 64);
        s2 += __shfl_xor(s2, o, 64);
    }
    if (lane == 0) {
        float mu = s * invM;
        float var = s2 * invM - mu * mu;
        float sc = g[c] * rsqrtf(var + 1e-5f);
        S[c] = sc;
        S[C + c] = be[c] - mu * sc;
    }
}

template <bool BF16OUT>
__global__ __launch_bounds__(256) void k_bnapply(const float* __restrict__ x0, const float* __restrict__ x1,
                                                 const float* __restrict__ ss, int C, int M,
                                                 float* __restrict__ of0, float* __restrict__ of1,
                                                 ushort* __restrict__ ob0, ushort* __restrict__ ob1) {
    int br = blockIdx.y;
    const float* x = br ? x1 : x0;
    const float* S = ss + br * 2 * C;
    int i = blockIdx.x * 256 + threadIdx.x;
    int total4 = M * C / 4;
    if (i >= total4) return;
    float4 v = *(const float4*)&x[(size_t)i * 4];
    int c0 = (i * 4) & (C - 1);
    float y0 = v.x * S[c0 + 0] + S[C + c0 + 0];
    float y1 = v.y * S[c0 + 1] + S[C + c0 + 1];
    float y2 = v.z * S[c0 + 2] + S[C + c0 + 2];
    float y3 = v.w * S[c0 + 3] + S[C + c0 + 3];
    y0 = y0 >= 0.f ? y0 : 0.01f * y0;
    y1 = y1 >= 0.f ? y1 : 0.01f * y1;
    y2 = y2 >= 0.f ? y2 : 0.01f * y2;
    y3 = y3 >= 0.f ? y3 : 0.01f * y3;
    if (BF16OUT) {
        ushort* ob = br ? ob1 : ob0;
        ushort4 o;
        o.x = f2bf(y0); o.y = f2bf(y1); o.z = f2bf(y2); o.w = f2bf(y3);
        *(ushort4*)&ob[(size_t)i * 4] = o;
    } else {
        float* of = br ? of1 : of0;
        float4 o = make_float4(y0, y1, y2, y3);
        *(float4*)&of[(size_t)i * 4] = o;
    }
}

// ---------------- pooling ----------------

__global__ void k_goff2(const int* __restrict__ bt, const int* __restrict__ bp, int* __restrict__ goff) {
    int tid = threadIdx.x;
    const int* b; int idx, slot;
    if (tid < 65) { b = bt; idx = tid; slot = tid; }
    else if (tid >= 128 && tid < 193) { b = bp; idx = tid - 128; slot = 65 + (tid - 128); }
    else return;
    int lo = 0, hi = NN;
    while (lo < hi) {
        int mid = (lo + hi) >> 1;
        if (b[mid] < idx) lo = mid + 1; else hi = mid;
    }
    goff[slot] = lo;
}

__global__ __launch_bounds__(512) void k_pool2(const float* __restrict__ xt, const float* __restrict__ xp,
                                               const int* __restrict__ goff, float* __restrict__ out) {
    int blk = blockIdx.x;
    int br = blk >> 6, b = blk & 63;
    const float* x = br ? xp : xt;
    const int* go = goff + br * 65;
    int t = threadIdx.x & 127, rg = threadIdx.x >> 7;
    __shared__ float sh[512];
    int s = go[b], e = go[b + 1];
    float acc = 0.f;
    for (int r = s + rg; r < e; r += 4) acc += x[(size_t)r * 128 + t];
    sh[threadIdx.x] = acc;
    __syncthreads();
    if (rg == 0) {
        float v = sh[t] + sh[128 + t] + sh[256 + t] + sh[384 + t];
        int cnt = e - s;
        out[(br * 64 + b) * 128 + t] = v / (float)(cnt > 0 ? cnt : 1);
    }
}

// ---------------- host orchestration ----------------

extern "C" void kernel_launch(void* const* d_in, const int* in_sizes, int n_in,
                              void* d_out, int out_size, void* d_ws, size_t ws_size,
                              hipStream_t stream) {
    const float* x_t = (const float*)d_in[0];
    const float* x_p = (const float*)d_in[1];
    const int* ei_t = (const int*)d_in[2];
    const int* et_t = (const int*)d_in[3];
    const int* bat_t = (const int*)d_in[4];
    const int* ei_p = (const int*)d_in[5];
    const int* et_p = (const int*)d_in[6];
    const int* bat_p = (const int*)d_in[7];
    const float* w_t1_rel = (const float*)d_in[8];
    const float* w_t1_root = (const float*)d_in[9];
    const float* b_t1 = (const float*)d_in[10];
    const float* w_t2_rel = (const float*)d_in[11];
    const float* w_t2_root = (const float*)d_in[12];
    const float* b_t2 = (const float*)d_in[13];
    const float* w_p1_rel = (const float*)d_in[14];
    const float* w_p1_root = (const float*)d_in[15];
    const float* b_p1 = (const float*)d_in[16];
    const float* w_p2_rel = (const float*)d_in[17];
    const float* w_p2_root = (const float*)d_in[18];
    const float* b_p2 = (const float*)d_in[19];
    const float* g_t1 = (const float*)d_in[20]; const float* be_t1 = (const float*)d_in[21];
    const float* g_t2 = (const float*)d_in[22]; const float* be_t2 = (const float*)d_in[23];
    const float* g_p1 = (const float*)d_in[24]; const float* be_p1 = (const float*)d_in[25];
    const float* g_p2 = (const float*)d_in[26]; const float* be_p2 = (const float*)d_in[27];

    char* wp = (char*)d_ws;
    auto alloc = [&](size_t b) -> void* {
        void* p = (void*)wp;
        wp += (b + 255) & ~(size_t)255;
        return p;
    };
    ushort* xt_bf = (ushort*)alloc((size_t)NN * 768 * 2);  // 30.72 MB; later: buf2t | buf2p | a1p
    ushort* xp_bf = (ushort*)alloc((size_t)NN * 128 * 2);
    ushort* h0b   = (ushort*)alloc((size_t)NN * 256 * 2);  // layer2: [h0t | h0p] halves
    ushort* h1b   = (ushort*)alloc((size_t)NN * 256 * 2);
    float* buf1   = (float*)alloc((size_t)NN * 256 * 4);   // shared sequentially t1 then p1
    ushort* a1t   = (ushort*)alloc((size_t)NN * 256 * 2);
    ushort* wtb   = (ushort*)alloc((size_t)(3 * 768 * 256 + 3 * 128 * 256 + 2 * 3 * 256 * 128) * 2);
    int* adj      = (int*)alloc((size_t)2 * NE * 4);
    int* posArr   = (int*)alloc((size_t)2 * NE * 4);
    int* off      = (int*)alloc((size_t)(2 * NN + 1) * 4);
    int* deg      = (int*)alloc((size_t)2 * NN * 4);
    int* csum     = (int*)alloc(256 * 4);
    float* part   = (float*)alloc((size_t)2 * 2 * 256 * BNG * 4);
    float* ss     = (float*)alloc(1024 * 4);
    int* goff     = (int*)alloc(130 * 4);

    // aliases inside dead xt_bf region (x_t bf16 consumed by t1 GEMM)
    float* buf2t = (float*)xt_bf;
    float* buf2p = buf2t + (size_t)NN * 128;
    ushort* a1p  = (ushort*)(buf2p + (size_t)NN * 128);

    ushort* wt_t1 = wtb;
    ushort* wt_p1 = wt_t1 + 3 * 768 * 256;
    ushort* wt_t2 = wt_p1 + 3 * 128 * 256;
    ushort* wt_p2 = wt_t2 + 3 * 256 * 128;

    dim3 blk(256);
    const int EB2 = (2 * NE) / 256;          // 2500
    const int SCB2 = (2 * NN + 255) / 256;   // 157
    const int nMT = (NN + 127) / 128;        // 157 row panels

    // ---- prep: CSR both branches (1 atomic/edge), casts ----
    hipMemsetAsync(deg, 0, (size_t)2 * NN * 4, stream);
    k_countpos<<<EB2, blk, 0, stream>>>(ei_t, ei_p, deg, posArr);
    k_scan_local<<<SCB2, blk, 0, stream>>>(deg, off, csum, 2 * NN);
    k_scan_csum<<<1, 256, 0, stream>>>(csum, off + 2 * NN, SCB2);
    k_scan_add<<<SCB2, blk, 0, stream>>>(off, csum, 2 * NN);
    k_fillpos<<<EB2, blk, 0, stream>>>(ei_t, et_t, ei_p, et_p, off, posArr, adj);

    int n4t = NN * 768 / 4, n4p = NN * 128 / 4;
    k_cast_x2<<<(n4t + n4p + 255) / 256, blk, 0, stream>>>(x_t, x_p, xt_bf, xp_bf, n4t, n4p);

    WtJob j0 = {w_t1_root, w_t1_rel, wt_t1, 768, 256};
    WtJob j1 = {w_p1_root, w_p1_rel, wt_p1, 128, 256};
    WtJob j2 = {w_t2_root, w_t2_rel, wt_t2, 256, 128};
    WtJob j3 = {w_p2_root, w_p2_rel, wt_p2, 256, 128};
    k_cast_wt_all<<<864, blk, 0, stream>>>(j0, j1, j2, j3, 576, 672, 768);

    GemmJob G;

    // ---- t layer 1: [20000,768] -> 256 ----
    G = {xt_bf, wt_t1, b_t1, buf1, h0b, h1b};
    k_gemm_mfma<<<2 * nMT * 3, blk, 0, stream>>>(G, G, 768, NN, 256, 1);
    k_agg256<<<NN / 2, blk, 0, stream>>>(off, adj, h0b, h1b, buf1);
    k_bnstats<<<dim3(BNG, 1), blk, 0, stream>>>(buf1, buf1, part, 256, NN);
    k_bnreduce<<<dim3(64, 1), blk, 0, stream>>>(part, g_t1, be_t1, g_t1, be_t1, ss, 256, 1.0f / NN);
    k_bnapply<true><<<dim3((NN * 256 / 4 + 255) / 256, 1), blk, 0, stream>>>(
        buf1, buf1, ss, 256, NN, nullptr, nullptr, a1t, a1t);

    // ---- p layer 1: [20000,128] -> 256 ----
    G = {xp_bf, wt_p1, b_p1, buf1, h0b, h1b};
    k_gemm_mfma<<<2 * nMT * 3, blk, 0, stream>>>(G, G, 128, NN, 256, 1);
    k_agg256<<<NN / 2, blk, 0, stream>>>(off + NN, adj, h0b, h1b, buf1);
    k_bnstats<<<dim3(BNG, 1), blk, 0, stream>>>(buf1, buf1, part, 256, NN);
    k_bnreduce<<<dim3(64, 1), blk, 0, stream>>>(part, g_p1, be_p1, g_p1, be_p1, ss, 256, 1.0f / NN);
    k_bnapply<true><<<dim3((NN * 256 / 4 + 255) / 256, 1), blk, 0, stream>>>(
        buf1, buf1, ss, 256, NN, nullptr, nullptr, a1p, a1p);

    // ---- layer 2, both branches merged: [20000,256] -> 128 ----
    ushort* h0t = h0b;                       ushort* h0p = h0b + (size_t)NN * 128;
    ushort* h1t = h1b;                       ushort* h1p = h1b + (size_t)NN * 128;
    GemmJob Gt = {a1t, wt_t2, b_t2, buf2t, h0t, h1t};
    GemmJob Gp = {a1p, wt_p2, b_p2, buf2p, h0p, h1p};
    k_gemm_mfma<<<1 * nMT * 3 * 2, blk, 0, stream>>>(Gt, Gp, 256, NN, 128, 2);
    k_agg128<<<2 * (NN / 4), blk, 0, stream>>>(off, adj, h0t, h1t, buf2t, h0p, h1p, buf2p);
    k_bnstats<<<dim3(BNG, 2), blk, 0, stream>>>(buf2t, buf2p, part, 128, NN);
    k_bnreduce<<<dim3(32, 2), blk, 0, stream>>>(part, g_t2, be_t2, g_p2, be_p2, ss, 128, 1.0f / NN);
    k_bnapply<false><<<dim3((NN * 128 / 4 + 255) / 256, 2), blk, 0, stream>>>(
        buf2t, buf2p, ss, 128, NN, buf2t, buf2p, nullptr, nullptr);

    // ---- pool both ----
    k_goff2<<<1, 256, 0, stream>>>(bat_t, bat_p, goff);
    k_pool2<<<128, 512, 0, stream>>>(buf2t, buf2p, goff, (float*)d_out);
}

// Round 8
// 359.566 us; speedup vs baseline: 3.8697x; 1.1437x over previous
//
#include <hip/hip_runtime.h>

#define NN 20000
#define NE 320000
#define NB 64
#define BNG 128  // bnstats partial-sum blocks

typedef __attribute__((ext_vector_type(4))) float f32x4;
typedef __attribute__((ext_vector_type(8))) __bf16 bf16x8;

static __device__ __forceinline__ ushort f2bf(float f) {
    uint u = __builtin_bit_cast(uint, f);
    uint r = (u + 0x7fffu + ((u >> 16) & 1u)) >> 16;
    return (ushort)r;
}
static __device__ __forceinline__ float bf2f(ushort u) {
    return __builtin_bit_cast(float, (uint)u << 16);
}

#define GLD_LDS16(g, l)                                                                     \
    __builtin_amdgcn_global_load_lds((__attribute__((address_space(1))) void*)(g),          \
                                     (__attribute__((address_space(3))) void*)(l), 16, 0, 0)

// ---------------- CSR build: ONE atomic per edge ----------------

__global__ __launch_bounds__(256) void k_countpos(const int* __restrict__ ei_t, const int* __restrict__ ei_p,
                                                  int* __restrict__ deg, int* __restrict__ posArr) {
    int e = blockIdx.x * 256 + threadIdx.x;
    if (e >= 2 * NE) return;
    int br = e >= NE;
    int el = e - br * NE;
    const int* ei = br ? ei_p : ei_t;
    int dst = ei[NE + el];
    posArr[e] = atomicAdd(&deg[br * NN + dst], 1);
}

__global__ __launch_bounds__(256) void k_scan_local(const int* __restrict__ deg, int* __restrict__ off,
                                                    int* __restrict__ csum, int n) {
    __shared__ int sh[256];
    int base = blockIdx.x * 256, tid = threadIdx.x;
    int v = (base + tid < n) ? deg[base + tid] : 0;
    sh[tid] = v; __syncthreads();
    for (int o = 1; o < 256; o <<= 1) {
        int t = (tid >= o) ? sh[tid - o] : 0;
        __syncthreads();
        sh[tid] += t;
        __syncthreads();
    }
    if (base + tid < n) off[base + tid] = sh[tid] - v;  // exclusive
    if (tid == 255) csum[blockIdx.x] = sh[255];
}

__global__ void k_scan_csum(int* __restrict__ csum, int* __restrict__ offN, int nc) {
    __shared__ int sh[256];
    int tid = threadIdx.x;
    int v = (tid < nc) ? csum[tid] : 0;
    sh[tid] = v; __syncthreads();
    for (int o = 1; o < 256; o <<= 1) {
        int t = (tid >= o) ? sh[tid - o] : 0;
        __syncthreads();
        sh[tid] += t;
        __syncthreads();
    }
    if (tid < nc) csum[tid] = sh[tid] - v;  // exclusive
    if (tid == 255) offN[0] = sh[255];
}

__global__ __launch_bounds__(256) void k_scan_add(int* __restrict__ off, const int* __restrict__ csum, int n) {
    int i = blockIdx.x * 256 + threadIdx.x;
    if (i < n) off[i] += csum[blockIdx.x];
}

__global__ __launch_bounds__(256) void k_fillpos(const int* __restrict__ ei_t, const int* __restrict__ et_t,
                                                 const int* __restrict__ ei_p, const int* __restrict__ et_p,
                                                 const int* __restrict__ off, const int* __restrict__ posArr,
                                                 int* __restrict__ adj) {
    int e = blockIdx.x * 256 + threadIdx.x;
    if (e >= 2 * NE) return;
    int br = e >= NE;
    int el = e - br * NE;
    const int* ei = br ? ei_p : ei_t;
    const int* et = br ? et_p : et_t;
    int src = ei[el], dst = ei[NE + el], r = et[el];
    int g = br * NN + dst;
    adj[off[g] + posArr[e]] = src | (r << 28);
}

// ---------------- casts ----------------

__global__ __launch_bounds__(256) void k_cast_x2(const float* __restrict__ xt, const float* __restrict__ xp,
                                                 ushort* __restrict__ ot, ushort* __restrict__ op,
                                                 int n4t, int n4p) {
    int i = blockIdx.x * 256 + threadIdx.x;
    const float* in; ushort* out; int j;
    if (i < n4t) { in = xt; out = ot; j = i; }
    else { j = i - n4t; if (j >= n4p) return; in = xp; out = op; }
    float4 v = *(const float4*)&in[(size_t)j * 4];
    ushort4 o;
    o.x = f2bf(v.x); o.y = f2bf(v.y); o.z = f2bf(v.z); o.w = f2bf(v.w);
    *(ushort4*)&out[(size_t)j * 4] = o;
}

struct WtJob { const float* root; const float* rel; ushort* dst; int K; int C; };

__global__ __launch_bounds__(256) void k_cast_wt_all(WtJob j0, WtJob j1, WtJob j2, WtJob j3,
                                                     int c1, int c2, int c3) {
    __shared__ float tile[32][33];
    int bid = blockIdx.x;
    WtJob j; int lt;
    if (bid < c1) { j = j0; lt = bid; }
    else if (bid < c2) { j = j1; lt = bid - c1; }
    else if (bid < c3) { j = j2; lt = bid - c2; }
    else { j = j3; lt = bid - c3; }
    int nx = j.K >> 5, ny = j.C >> 5;
    int mat = lt / (nx * ny);
    int r2 = lt - mat * (nx * ny);
    int kx = r2 % nx, cy = r2 / nx;
    int KC = j.K * j.C;
    const float* W = (mat == 0) ? j.root : j.rel + (size_t)(mat - 1) * KC;
    int k0 = kx * 32, c0 = cy * 32;
    int tx = threadIdx.x & 31, ty = threadIdx.x >> 5;
#pragma unroll
    for (int i = 0; i < 4; i++)
        tile[ty + i * 8][tx] = W[(size_t)(k0 + ty + i * 8) * j.C + c0 + tx];
    __syncthreads();
#pragma unroll
    for (int i = 0; i < 4; i++)
        j.dst[(size_t)mat * KC + (size_t)(c0 + ty + i * 8) * j.K + k0 + tx] = f2bf(tile[tx][ty + i * 8]);
}

// ---------------- MFMA GEMM: 3 products/job (root->fp32+bias, rel0/rel1->bf16) ----------------
// Per-job K (merged l1: K=768 and K=128 in one dispatch). 128x128 tile, XCD-chunk swizzle.

struct GemmJob { const ushort* A; const ushort* Wt; const float* bias;
                 float* Droot; ushort* h0; ushort* h1; int K; };

__global__ __launch_bounds__(256, 4) void k_gemm_mfma(GemmJob j0, GemmJob j1, int M, int C, int NBR) {
    __shared__ ushort smem[2 * 128 * 64];
    ushort* As = smem;
    ushort* Bs = smem + 128 * 64;

    int nx = C >> 7;
    int perY = nx * 3 * NBR;
    int nwg = gridDim.x;
    int orig = blockIdx.x;
    int q = nwg >> 3, r = nwg & 7;
    int xcd = orig & 7, pos = orig >> 3;
    int wgid = (xcd < r) ? (xcd * (q + 1) + pos) : (r * (q + 1) + (xcd - r) * q + pos);
    int y = wgid / perY, rem = wgid - y * perY;
    int x = rem / (3 * NBR), zz = rem - x * (3 * NBR);
    int br = zz / 3, z = zz - br * 3;
    GemmJob j = br ? j1 : j0;
    int K = j.K;

    const ushort* B = j.Wt + (size_t)z * C * K;
    int tid = threadIdx.x;
    int lane = tid & 63, wave = tid >> 6;
    int wr = wave >> 1, wc = wave & 1;
    int rowTile = y * 128, colTile = x * 128;

    f32x4 acc[4][4] = {};

    for (int k0 = 0; k0 < K; k0 += 64) {
        __syncthreads();
#pragma unroll
        for (int i = 0; i < 4; i++) {
            int id = i * 256 + tid;
            int rr = id >> 3, ck = id & 7;
            int garow = rowTile + rr;
            if (garow >= M) garow = M - 1;
            GLD_LDS16(j.A + (size_t)garow * K + k0 + ck * 8, &As[id * 8]);
            GLD_LDS16(B + (size_t)(colTile + rr) * K + k0 + ck * 8, &Bs[id * 8]);
        }
        __syncthreads();
#pragma unroll
        for (int kk = 0; kk < 2; kk++) {
            int kb = kk * 32 + (lane >> 4) * 8;
            bf16x8 af[4], bfr[4];
#pragma unroll
            for (int mi = 0; mi < 4; mi++)
                af[mi] = *(const bf16x8*)&As[(wr * 64 + mi * 16 + (lane & 15)) * 64 + kb];
#pragma unroll
            for (int ni = 0; ni < 4; ni++)
                bfr[ni] = *(const bf16x8*)&Bs[(wc * 64 + ni * 16 + (lane & 15)) * 64 + kb];
#pragma unroll
            for (int mi = 0; mi < 4; mi++)
#pragma unroll
                for (int ni = 0; ni < 4; ni++)
                    acc[mi][ni] = __builtin_amdgcn_mfma_f32_16x16x32_bf16(af[mi], bfr[ni], acc[mi][ni], 0, 0, 0);
        }
    }

    int lc = lane & 15, lr4 = (lane >> 4) * 4;
    if (z == 0) {
#pragma unroll
        for (int ni = 0; ni < 4; ni++) {
            int col = colTile + wc * 64 + ni * 16 + lc;
            float bj = j.bias[col];
#pragma unroll
            for (int mi = 0; mi < 4; mi++) {
#pragma unroll
                for (int jj = 0; jj < 4; jj++) {
                    int row = rowTile + wr * 64 + mi * 16 + lr4 + jj;
                    if (row < M) j.Droot[(size_t)row * C + col] = acc[mi][ni][jj] + bj;
                }
            }
        }
    } else {
        ushort* H = (z == 1) ? j.h0 : j.h1;
        __syncthreads();
        ushort* Ep = smem;  // [128][128] ushorts = 32 KB
#pragma unroll
        for (int ni = 0; ni < 4; ni++) {
            int col = wc * 64 + ni * 16 + lc;
#pragma unroll
            for (int mi = 0; mi < 4; mi++) {
#pragma unroll
                for (int jj = 0; jj < 4; jj++) {
                    int rloc = wr * 64 + mi * 16 + lr4 + jj;
                    int chunk = (col >> 3) ^ (rloc & 7);
                    Ep[rloc * 128 + (chunk << 3) + (col & 7)] = f2bf(acc[mi][ni][jj]);
                }
            }
        }
        __syncthreads();
#pragma unroll
        for (int it = 0; it < 8; it++) {
            int cid = it * 256 + tid;
            int rloc = cid >> 4, cc = cid & 15;
            int grow = rowTile + rloc;
            if (grow < M) {
                int4 v = *(const int4*)&Ep[rloc * 128 + ((cc ^ (rloc & 7)) << 3)];
                *(int4*)&H[(size_t)grow * C + colTile + cc * 8] = v;
            }
        }
    }
}

// ---------------- aggregation: out += sum_r sum(h_r[src]) / max(cnt_r,1) ----------------
// C=256, optionally 2 branches in one grid (perBr blocks each; 2 nodes/block, 2 waves/node).

__global__ __launch_bounds__(256) void k_agg256(const int* __restrict__ off, const int* __restrict__ adj,
                                                const ushort* __restrict__ h0t, const ushort* __restrict__ h1t,
                                                float* __restrict__ outt,
                                                const ushort* __restrict__ h0p, const ushort* __restrict__ h1p,
                                                float* __restrict__ outp, int perBr) {
    __shared__ float4 shA[2][64];
    __shared__ float4 shB[2][64];
    __shared__ int shc[2][2];
    int br = blockIdx.x >= perBr;
    int bb = blockIdx.x - br * perBr;
    const int* offb = off + br * NN;
    const ushort* h0 = br ? h0p : h0t;
    const ushort* h1 = br ? h1p : h1t;
    float* out = br ? outp : outt;
    int wave = threadIdx.x >> 6, lane = threadIdx.x & 63;
    int nb = wave >> 1, w = wave & 1;
    int node = bb * 2 + nb;
    int s = offb[node], e = offb[node + 1];
    int len = e - s;
    int mid = s + ((len + 1) >> 1);
    int i0 = w ? mid : s;
    int i1 = w ? e : mid;
    float4 a0 = make_float4(0.f, 0.f, 0.f, 0.f);
    float4 a1 = make_float4(0.f, 0.f, 0.f, 0.f);
    float4 b0 = make_float4(0.f, 0.f, 0.f, 0.f);
    float4 b1 = make_float4(0.f, 0.f, 0.f, 0.f);
    int c0 = 0, c1 = 0;
    int i = i0;
    for (; i + 1 < i1; i += 2) {
        int v0 = adj[i], v1 = adj[i + 1];
        int s0 = v0 & 0x0FFFFFFF, r0 = v0 >> 28;
        int s1 = v1 & 0x0FFFFFFF, r1 = v1 >> 28;
        const ushort* hp0 = r0 ? h1 : h0;
        const ushort* hp1 = r1 ? h1 : h0;
        ushort4 x0 = *(const ushort4*)&hp0[(size_t)s0 * 256 + lane * 4];
        ushort4 x1 = *(const ushort4*)&hp1[(size_t)s1 * 256 + lane * 4];
        if (r0) { a1.x += bf2f(x0.x); a1.y += bf2f(x0.y); a1.z += bf2f(x0.z); a1.w += bf2f(x0.w); c1++; }
        else    { a0.x += bf2f(x0.x); a0.y += bf2f(x0.y); a0.z += bf2f(x0.z); a0.w += bf2f(x0.w); c0++; }
        if (r1) { b1.x += bf2f(x1.x); b1.y += bf2f(x1.y); b1.z += bf2f(x1.z); b1.w += bf2f(x1.w); c1++; }
        else    { b0.x += bf2f(x1.x); b0.y += bf2f(x1.y); b0.z += bf2f(x1.z); b0.w += bf2f(x1.w); c0++; }
    }
    if (i < i1) {
        int v0 = adj[i];
        int s0 = v0 & 0x0FFFFFFF, r0 = v0 >> 28;
        const ushort* hp0 = r0 ? h1 : h0;
        ushort4 x0 = *(const ushort4*)&hp0[(size_t)s0 * 256 + lane * 4];
        if (r0) { a1.x += bf2f(x0.x); a1.y += bf2f(x0.y); a1.z += bf2f(x0.z); a1.w += bf2f(x0.w); c1++; }
        else    { a0.x += bf2f(x0.x); a0.y += bf2f(x0.y); a0.z += bf2f(x0.z); a0.w += bf2f(x0.w); c0++; }
    }
    float4 s0v = make_float4(a0.x + b0.x, a0.y + b0.y, a0.z + b0.z, a0.w + b0.w);
    float4 s1v = make_float4(a1.x + b1.x, a1.y + b1.y, a1.z + b1.z, a1.w + b1.w);
    if (w) {
        shA[nb][lane] = s0v; shB[nb][lane] = s1v;
        if (lane == 0) { shc[nb][0] = c0; shc[nb][1] = c1; }
    }
    __syncthreads();
    if (!w) {
        float4 t0 = shA[nb][lane], t1 = shB[nb][lane];
        c0 += shc[nb][0]; c1 += shc[nb][1];
        float w0 = 1.0f / (float)(c0 > 0 ? c0 : 1);
        float w1 = 1.0f / (float)(c1 > 0 ? c1 : 1);
        float* p = &out[(size_t)node * 256 + lane * 4];
        float4 o = *(float4*)p;
        o.x += (s0v.x + t0.x) * w0 + (s1v.x + t1.x) * w1;
        o.y += (s0v.y + t0.y) * w0 + (s1v.y + t1.y) * w1;
        o.z += (s0v.z + t0.z) * w0 + (s1v.z + t1.z) * w1;
        o.w += (s0v.w + t0.w) * w0 + (s1v.w + t1.w) * w1;
        *(float4*)p = o;
    }
}

// C=128 merged (both branches): 4 nodes/block (wave each), lane-parity edge split x 2 chains.
__global__ __launch_bounds__(256) void k_agg128(const int* __restrict__ offAll, const int* __restrict__ adj,
                                                const ushort* __restrict__ h0t, const ushort* __restrict__ h1t,
                                                float* __restrict__ outt,
                                                const ushort* __restrict__ h0p, const ushort* __restrict__ h1p,
                                                float* __restrict__ outp) {
    int half = gridDim.x >> 1;
    int br = blockIdx.x >= half;
    int bb = blockIdx.x - br * half;
    int wave = threadIdx.x >> 6, lane = threadIdx.x & 63;
    int node = bb * 4 + wave;
    const int* off = offAll + br * NN;
    const ushort* h0 = br ? h0p : h0t;
    const ushort* h1 = br ? h1p : h1t;
    float* out = br ? outp : outt;
    int s = off[node], e = off[node + 1];
    int l32 = lane & 31, ep = lane >> 5;
    float4 a0 = make_float4(0.f, 0.f, 0.f, 0.f);
    float4 a1 = make_float4(0.f, 0.f, 0.f, 0.f);
    float4 b0 = make_float4(0.f, 0.f, 0.f, 0.f);
    float4 b1 = make_float4(0.f, 0.f, 0.f, 0.f);
    int c0 = 0, c1 = 0;
    int i = s + ep;
    for (; i + 2 < e; i += 4) {
        int v0 = adj[i], v1 = adj[i + 2];
        int s0 = v0 & 0x0FFFFFFF, r0 = v0 >> 28;
        int s1 = v1 & 0x0FFFFFFF, r1 = v1 >> 28;
        const ushort* hp0 = r0 ? h1 : h0;
        const ushort* hp1 = r1 ? h1 : h0;
        ushort4 x0 = *(const ushort4*)&hp0[(size_t)s0 * 128 + l32 * 4];
        ushort4 x1 = *(const ushort4*)&hp1[(size_t)s1 * 128 + l32 * 4];
        if (r0) { a1.x += bf2f(x0.x); a1.y += bf2f(x0.y); a1.z += bf2f(x0.z); a1.w += bf2f(x0.w); c1++; }
        else    { a0.x += bf2f(x0.x); a0.y += bf2f(x0.y); a0.z += bf2f(x0.z); a0.w += bf2f(x0.w); c0++; }
        if (r1) { b1.x += bf2f(x1.x); b1.y += bf2f(x1.y); b1.z += bf2f(x1.z); b1.w += bf2f(x1.w); c1++; }
        else    { b0.x += bf2f(x1.x); b0.y += bf2f(x1.y); b0.z += bf2f(x1.z); b0.w += bf2f(x1.w); c0++; }
    }
    if (i < e) {
        int v0 = adj[i];
        int s0 = v0 & 0x0FFFFFFF, r0 = v0 >> 28;
        const ushort* hp0 = r0 ? h1 : h0;
        ushort4 x0 = *(const ushort4*)&hp0[(size_t)s0 * 128 + l32 * 4];
        if (r0) { a1.x += bf2f(x0.x); a1.y += bf2f(x0.y); a1.z += bf2f(x0.z); a1.w += bf2f(x0.w); c1++; }
        else    { a0.x += bf2f(x0.x); a0.y += bf2f(x0.y); a0.z += bf2f(x0.z); a0.w += bf2f(x0.w); c0++; }
    }
    float sx0 = a0.x + b0.x, sy0 = a0.y + b0.y, sz0 = a0.z + b0.z, sw0 = a0.w + b0.w;
    float sx1 = a1.x + b1.x, sy1 = a1.y + b1.y, sz1 = a1.z + b1.z, sw1 = a1.w + b1.w;
    sx0 += __shfl_xor(sx0, 32); sy0 += __shfl_xor(sy0, 32);
    sz0 += __shfl_xor(sz0, 32); sw0 += __shfl_xor(sw0, 32);
    sx1 += __shfl_xor(sx1, 32); sy1 += __shfl_xor(sy1, 32);
    sz1 += __shfl_xor(sz1, 32); sw1 += __shfl_xor(sw1, 32);
    c0 += __shfl_xor(c0, 32); c1 += __shfl_xor(c1, 32);
    if (ep == 0) {
        float w0 = 1.0f / (float)(c0 > 0 ? c0 : 1);
        float w1 = 1.0f / (float)(c1 > 0 ? c1 : 1);
        float* p = &out[(size_t)node * 128 + l32 * 4];
        float4 o = *(float4*)p;
        o.x += sx0 * w0 + sx1 * w1;
        o.y += sy0 * w0 + sy1 * w1;
        o.z += sz0 * w0 + sz1 * w1;
        o.w += sw0 * w0 + sw1 * w1;
        *(float4*)p = o;
    }
}

// ---------------- batchnorm + leaky (atomic-free two-stage stats; 2-branch grid.y) ----

__global__ __launch_bounds__(256) void k_bnstats(const float* __restrict__ x0, const float* __restrict__ x1,
                                                 float* __restrict__ part, int C, int M) {
    int br = blockIdx.y;
    const float* x = br ? x1 : x0;
    float* P = part + (size_t)br * 2 * C * BNG;
    int tid = threadIdx.x;
    int groups = 256 / C;
    int col = tid & (C - 1);
    int rg = tid / C;
    float s = 0.f, s2 = 0.f;
    for (int row = blockIdx.x * groups + rg; row < M; row += BNG * groups) {
        float v = x[(size_t)row * C + col];
        s += v; s2 += v * v;
    }
    __shared__ float shs[256], shq[256];
    shs[tid] = s; shq[tid] = s2;
    __syncthreads();
    if (tid < C) {
        for (int g = 1; g < groups; g++) { shs[tid] += shs[tid + g * C]; shq[tid] += shq[tid + g * C]; }
        P[(size_t)tid * BNG + blockIdx.x] = shs[tid];
        P[(size_t)(C + tid) * BNG + blockIdx.x] = shq[tid];
    }
}

__global__ __launch_bounds__(256) void k_bnreduce(const float* __restrict__ part,
                                                  const float* __restrict__ g0, const float* __restrict__ be0,
                                                  const float* __restrict__ g1, const float* __restrict__ be1,
                                                  float* __restrict__ ss, int C, float invM) {
    int br = blockIdx.y;
    const float* P = part + (size_t)br * 2 * C * BNG;
    const float* g = br ? g1 : g0;
    const float* be = br ? be1 : be0;
    float* S = ss + br * 2 * C;
    int wv = threadIdx.x >> 6, lane = threadIdx.x & 63;
    int c = blockIdx.x * 4 + wv;
    if (c >= C) return;
    float s = P[(size_t)c * BNG + lane] + P[(size_t)c * BNG + 64 + lane];
    float s2 = P[(size_t)(C + c) * BNG + lane] + P[(size_t)(C + c) * BNG + 64 + lane];
#pragma unroll
    for (int o = 32; o >= 1; o >>= 1) {
        s += __shfl_xor(s, o, 64);
        s2 += __shfl_xor(s2, o, 64);
    }
    if (lane == 0) {
        float mu = s * invM;
        float var = s2 * invM - mu * mu;
        float sc = g[c] * rsqrtf(var + 1e-5f);
        S[c] = sc;
        S[C + c] = be[c] - mu * sc;
    }
}

template <bool BF16OUT>
__global__ __launch_bounds__(256) void k_bnapply(const float* __restrict__ x0, const float* __restrict__ x1,
                                                 const float* __restrict__ ss, int C, int M,
                                                 float* __restrict__ of0, float* __restrict__ of1,
                                                 ushort* __restrict__ ob0, ushort* __restrict__ ob1) {
    int br = blockIdx.y;
    const float* x = br ? x1 : x0;
    const float* S = ss + br * 2 * C;
    int i = blockIdx.x * 256 + threadIdx.x;
    int total4 = M * C / 4;
    if (i >= total4) return;
    float4 v = *(const float4*)&x[(size_t)i * 4];
    int c0 = (i * 4) & (C - 1);
    float y0 = v.x * S[c0 + 0] + S[C + c0 + 0];
    float y1 = v.y * S[c0 + 1] + S[C + c0 + 1];
    float y2 = v.z * S[c0 + 2] + S[C + c0 + 2];
    float y3 = v.w * S[c0 + 3] + S[C + c0 + 3];
    y0 = y0 >= 0.f ? y0 : 0.01f * y0;
    y1 = y1 >= 0.f ? y1 : 0.01f * y1;
    y2 = y2 >= 0.f ? y2 : 0.01f * y2;
    y3 = y3 >= 0.f ? y3 : 0.01f * y3;
    if (BF16OUT) {
        ushort* ob = br ? ob1 : ob0;
        ushort4 o;
        o.x = f2bf(y0); o.y = f2bf(y1); o.z = f2bf(y2); o.w = f2bf(y3);
        *(ushort4*)&ob[(size_t)i * 4] = o;
    } else {
        float* of = br ? of1 : of0;
        float4 o = make_float4(y0, y1, y2, y3);
        *(float4*)&of[(size_t)i * 4] = o;
    }
}

// ---------------- pooling ----------------

__global__ void k_goff2(const int* __restrict__ bt, const int* __restrict__ bp, int* __restrict__ goff) {
    int tid = threadIdx.x;
    const int* b; int idx, slot;
    if (tid < 65) { b = bt; idx = tid; slot = tid; }
    else if (tid >= 128 && tid < 193) { b = bp; idx = tid - 128; slot = 65 + (tid - 128); }
    else return;
    int lo = 0, hi = NN;
    while (lo < hi) {
        int mid = (lo + hi) >> 1;
        if (b[mid] < idx) lo = mid + 1; else hi = mid;
    }
    goff[slot] = lo;
}

__global__ __launch_bounds__(512) void k_pool2(const float* __restrict__ xt, const float* __restrict__ xp,
                                               const int* __restrict__ goff, float* __restrict__ out) {
    int blk = blockIdx.x;
    int br = blk >> 6, b = blk & 63;
    const float* x = br ? xp : xt;
    const int* go = goff + br * 65;
    int t = threadIdx.x & 127, rg = threadIdx.x >> 7;
    __shared__ float sh[512];
    int s = go[b], e = go[b + 1];
    float acc = 0.f;
    for (int r = s + rg; r < e; r += 4) acc += x[(size_t)r * 128 + t];
    sh[threadIdx.x] = acc;
    __syncthreads();
    if (rg == 0) {
        float v = sh[t] + sh[128 + t] + sh[256 + t] + sh[384 + t];
        int cnt = e - s;
        out[(br * 64 + b) * 128 + t] = v / (float)(cnt > 0 ? cnt : 1);
    }
}

// ---------------- host orchestration ----------------

extern "C" void kernel_launch(void* const* d_in, const int* in_sizes, int n_in,
                              void* d_out, int out_size, void* d_ws, size_t ws_size,
                              hipStream_t stream) {
    const float* x_t = (const float*)d_in[0];
    const float* x_p = (const float*)d_in[1];
    const int* ei_t = (const int*)d_in[2];
    const int* et_t = (const int*)d_in[3];
    const int* bat_t = (const int*)d_in[4];
    const int* ei_p = (const int*)d_in[5];
    const int* et_p = (const int*)d_in[6];
    const int* bat_p = (const int*)d_in[7];
    const float* w_t1_rel = (const float*)d_in[8];
    const float* w_t1_root = (const float*)d_in[9];
    const float* b_t1 = (const float*)d_in[10];
    const float* w_t2_rel = (const float*)d_in[11];
    const float* w_t2_root = (const float*)d_in[12];
    const float* b_t2 = (const float*)d_in[13];
    const float* w_p1_rel = (const float*)d_in[14];
    const float* w_p1_root = (const float*)d_in[15];
    const float* b_p1 = (const float*)d_in[16];
    const float* w_p2_rel = (const float*)d_in[17];
    const float* w_p2_root = (const float*)d_in[18];
    const float* b_p2 = (const float*)d_in[19];
    const float* g_t1 = (const float*)d_in[20]; const float* be_t1 = (const float*)d_in[21];
    const float* g_t2 = (const float*)d_in[22]; const float* be_t2 = (const float*)d_in[23];
    const float* g_p1 = (const float*)d_in[24]; const float* be_p1 = (const float*)d_in[25];
    const float* g_p2 = (const float*)d_in[26]; const float* be_p2 = (const float*)d_in[27];

    char* wp = (char*)d_ws;
    auto alloc = [&](size_t b) -> void* {
        void* p = (void*)wp;
        wp += (b + 255) & ~(size_t)255;
        return p;
    };

    const bool MERGED = ws_size >= (size_t)137 * 1000 * 1000;

    dim3 blk(256);
    const int EB2 = (2 * NE) / 256;
    const int SCB2 = (2 * NN + 255) / 256;
    const int nMT = (NN + 127) / 128;

    // common small buffers allocated identically in both modes at the END region
    ushort* xt_bf; ushort* xp_bf;
    ushort *h0t1, *h1t1, *h0p1, *h1p1;     // l1 h outputs (merged: 4 bufs; seq: h0b/h1b reused)
    float *buf1t, *buf1p;                  // l1 root+agg accum (seq: same buffer)
    ushort *a1t, *a1p;
    float *buf2t, *buf2p;
    ushort *h0t2, *h1t2, *h0p2, *h1p2;     // l2 h outputs
    ushort* wtb; int* adj; int* posArr; int* off; int* deg; int* csum;
    float* part; float* ss; int* goff;

    if (MERGED) {
        xt_bf = (ushort*)alloc((size_t)NN * 768 * 2);   // dead after l1 GEMM -> buf2t|buf2p|a1p
        xp_bf = (ushort*)alloc((size_t)NN * 128 * 2);
        h0t1 = (ushort*)alloc((size_t)NN * 256 * 2);
        h1t1 = (ushort*)alloc((size_t)NN * 256 * 2);
        h0p1 = (ushort*)alloc((size_t)NN * 256 * 2);
        h1p1 = (ushort*)alloc((size_t)NN * 256 * 2);
        buf1t = (float*)alloc((size_t)NN * 256 * 4);
        buf1p = (float*)alloc((size_t)NN * 256 * 4);
        a1t = (ushort*)alloc((size_t)NN * 256 * 2);
        wtb = (ushort*)alloc((size_t)(3 * 768 * 256 + 3 * 128 * 256 + 2 * 3 * 256 * 128) * 2);
        adj = (int*)alloc((size_t)2 * NE * 4);
        posArr = (int*)alloc((size_t)2 * NE * 4);
        off = (int*)alloc((size_t)(2 * NN + 1) * 4);
        deg = (int*)alloc((size_t)2 * NN * 4);
        csum = (int*)alloc(256 * 4);
        part = (float*)alloc((size_t)2 * 2 * 256 * BNG * 4);
        ss = (float*)alloc(1024 * 4);
        goff = (int*)alloc(130 * 4);
        // aliases in dead xt_bf region (30.72 MB = 10.24*3)
        buf2t = (float*)xt_bf;
        buf2p = buf2t + (size_t)NN * 128;
        a1p = (ushort*)(buf2p + (size_t)NN * 128);
        // l2 h aliases in dead l1-h regions (h0t1/h1t1 dead after l1 agg)
        h0t2 = h0t1;                       h0p2 = h0t1 + (size_t)NN * 128;
        h1t2 = h1t1;                       h1p2 = h1t1 + (size_t)NN * 128;
    } else {
        // R7 layout (~95 MB)
        xt_bf = (ushort*)alloc((size_t)NN * 768 * 2);
        xp_bf = (ushort*)alloc((size_t)NN * 128 * 2);
        ushort* h0b = (ushort*)alloc((size_t)NN * 256 * 2);
        ushort* h1b = (ushort*)alloc((size_t)NN * 256 * 2);
        float* buf1 = (float*)alloc((size_t)NN * 256 * 4);
        a1t = (ushort*)alloc((size_t)NN * 256 * 2);
        wtb = (ushort*)alloc((size_t)(3 * 768 * 256 + 3 * 128 * 256 + 2 * 3 * 256 * 128) * 2);
        adj = (int*)alloc((size_t)2 * NE * 4);
        posArr = (int*)alloc((size_t)2 * NE * 4);
        off = (int*)alloc((size_t)(2 * NN + 1) * 4);
        deg = (int*)alloc((size_t)2 * NN * 4);
        csum = (int*)alloc(256 * 4);
        part = (float*)alloc((size_t)2 * 2 * 256 * BNG * 4);
        ss = (float*)alloc(1024 * 4);
        goff = (int*)alloc(130 * 4);
        h0t1 = h0b; h1t1 = h1b; h0p1 = h0b; h1p1 = h1b;
        buf1t = buf1; buf1p = buf1;
        buf2t = (float*)xt_bf;
        buf2p = buf2t + (size_t)NN * 128;
        a1p = (ushort*)(buf2p + (size_t)NN * 128);
        h0t2 = h0b;                        h0p2 = h0b + (size_t)NN * 128;
        h1t2 = h1b;                        h1p2 = h1b + (size_t)NN * 128;
    }

    // ---- prep: CSR both branches (1 atomic/edge), casts ----
    hipMemsetAsync(deg, 0, (size_t)2 * NN * 4, stream);
    k_countpos<<<EB2, blk, 0, stream>>>(ei_t, ei_p, deg, posArr);
    k_scan_local<<<SCB2, blk, 0, stream>>>(deg, off, csum, 2 * NN);
    k_scan_csum<<<1, 256, 0, stream>>>(csum, off + 2 * NN, SCB2);
    k_scan_add<<<SCB2, blk, 0, stream>>>(off, csum, 2 * NN);
    k_fillpos<<<EB2, blk, 0, stream>>>(ei_t, et_t, ei_p, et_p, off, posArr, adj);

    int n4t = NN * 768 / 4, n4p = NN * 128 / 4;
    k_cast_x2<<<(n4t + n4p + 255) / 256, blk, 0, stream>>>(x_t, x_p, xt_bf, xp_bf, n4t, n4p);

    ushort* wt_t1 = wtb;
    ushort* wt_p1 = wt_t1 + 3 * 768 * 256;
    ushort* wt_t2 = wt_p1 + 3 * 128 * 256;
    ushort* wt_p2 = wt_t2 + 3 * 256 * 128;
    WtJob j0 = {w_t1_root, w_t1_rel, wt_t1, 768, 256};
    WtJob j1 = {w_p1_root, w_p1_rel, wt_p1, 128, 256};
    WtJob j2 = {w_t2_root, w_t2_rel, wt_t2, 256, 128};
    WtJob j3 = {w_p2_root, w_p2_rel, wt_p2, 256, 128};
    k_cast_wt_all<<<864, blk, 0, stream>>>(j0, j1, j2, j3, 576, 672, 768);

    GemmJob Gt1 = {xt_bf, wt_t1, b_t1, buf1t, h0t1, h1t1, 768};
    GemmJob Gp1 = {xp_bf, wt_p1, b_p1, buf1p, h0p1, h1p1, 128};

    if (MERGED) {
        // ---- layer 1, both branches in one set of dispatches ----
        k_gemm_mfma<<<2 * nMT * 3 * 2, blk, 0, stream>>>(Gt1, Gp1, NN, 256, 2);
        k_agg256<<<NN, blk, 0, stream>>>(off, adj, h0t1, h1t1, buf1t, h0p1, h1p1, buf1p, NN / 2);
        k_bnstats<<<dim3(BNG, 2), blk, 0, stream>>>(buf1t, buf1p, part, 256, NN);
        k_bnreduce<<<dim3(64, 2), blk, 0, stream>>>(part, g_t1, be_t1, g_p1, be_p1, ss, 256, 1.0f / NN);
        k_bnapply<true><<<dim3((NN * 256 / 4 + 255) / 256, 2), blk, 0, stream>>>(
            buf1t, buf1p, ss, 256, NN, nullptr, nullptr, a1t, a1p);
    } else {
        // ---- layer 1 sequential (R7 path) ----
        k_gemm_mfma<<<2 * nMT * 3, blk, 0, stream>>>(Gt1, Gt1, NN, 256, 1);
        k_agg256<<<NN / 2, blk, 0, stream>>>(off, adj, h0t1, h1t1, buf1t, h0t1, h1t1, buf1t, NN / 2);
        k_bnstats<<<dim3(BNG, 1), blk, 0, stream>>>(buf1t, buf1t, part, 256, NN);
        k_bnreduce<<<dim3(64, 1), blk, 0, stream>>>(part, g_t1, be_t1, g_t1, be_t1, ss, 256, 1.0f / NN);
        k_bnapply<true><<<dim3((NN * 256 / 4 + 255) / 256, 1), blk, 0, stream>>>(
            buf1t, buf1t, ss, 256, NN, nullptr, nullptr, a1t, a1t);

        k_gemm_mfma<<<2 * nMT * 3, blk, 0, stream>>>(Gp1, Gp1, NN, 256, 1);
        k_agg256<<<NN / 2, blk, 0, stream>>>(off + NN, adj, h0p1, h1p1, buf1p, h0p1, h1p1, buf1p, NN / 2);
        k_bnstats<<<dim3(BNG, 1), blk, 0, stream>>>(buf1p, buf1p, part, 256, NN);
        k_bnreduce<<<dim3(64, 1), blk, 0, stream>>>(part, g_p1, be_p1, g_p1, be_p1, ss, 256, 1.0f / NN);
        k_bnapply<true><<<dim3((NN * 256 / 4 + 255) / 256, 1), blk, 0, stream>>>(
            buf1p, buf1p, ss, 256, NN, nullptr, nullptr, a1p, a1p);
    }

    // ---- layer 2, both branches merged (both modes) ----
    GemmJob Gt2 = {a1t, wt_t2, b_t2, buf2t, h0t2, h1t2, 256};
    GemmJob Gp2 = {a1p, wt_p2, b_p2, buf2p, h0p2, h1p2, 256};
    k_gemm_mfma<<<1 * nMT * 3 * 2, blk, 0, stream>>>(Gt2, Gp2, NN, 128, 2);
    k_agg128<<<2 * (NN / 4), blk, 0, stream>>>(off, adj, h0t2, h1t2, buf2t, h0p2, h1p2, buf2p);
    k_bnstats<<<dim3(BNG, 2), blk, 0, stream>>>(buf2t, buf2p, part, 128, NN);
    k_bnreduce<<<dim3(32, 2), blk, 0, stream>>>(part, g_t2, be_t2, g_p2, be_p2, ss, 128, 1.0f / NN);
    k_bnapply<false><<<dim3((NN * 128 / 4 + 255) / 256, 2), blk, 0, stream>>>(
        buf2t, buf2p, ss, 128, NN, buf2t, buf2p, nullptr, nullptr);

    // ---- pool both ----
    k_goff2<<<1, 256, 0, stream>>>(bat_t, bat_p, goff);
    k_pool2<<<128, 512, 0, stream>>>(buf2t, buf2p, goff, (float*)d_out);
}